// Round 2
// baseline (2392.833 us; speedup 1.0000x reference)
//
#include <hip/hip_runtime.h>
#include <hip/hip_bf16.h>
#include <math.h>

typedef unsigned short u16;
typedef unsigned int   u32;

#define B_  4
#define T_  4096
#define H_  16
#define HD_ 64
#define DK_ 1024
#define S_  128
#define BH_ (B_*H_)      // 64
#define M_  (B_*T_)      // 16384

__device__ __forceinline__ float bf2f(u16 u) { return __uint_as_float(((u32)u) << 16); }
__device__ __forceinline__ u16 f2bf(float f) {
    u32 x = __float_as_uint(f);
    u32 r = (x + 0x7fffu + ((x >> 16) & 1u)) >> 16;   // round-to-nearest-even
    return (u16)r;
}

// ---------------------------------------------------------------------------
// QKV GEMM: C[m][n] = sum_k x[m][k] * W[n][k], written bf16 into (B,H,T,64)
// 128x128 tile, BK=16, 256 threads, 8x8 micro-tile, k-major LDS (+4 pad).
// blockIdx.z selects Wq/Wk/Wv -> Qb/Kb/Vb.
// ---------------------------------------------------------------------------
__global__ __launch_bounds__(256)
void qkv_gemm(const float* __restrict__ x,
              const float* __restrict__ Wq, const float* __restrict__ Wk,
              const float* __restrict__ Wv,
              u16* __restrict__ Qb, u16* __restrict__ Kb, u16* __restrict__ Vb)
{
    __shared__ float As[16 * 132];
    __shared__ float Bs[16 * 132];
    const float* W = (blockIdx.z == 0) ? Wq : (blockIdx.z == 1) ? Wk : Wv;
    u16* C = (blockIdx.z == 0) ? Qb : (blockIdx.z == 1) ? Kb : Vb;

    int tid = threadIdx.x;
    int row0 = blockIdx.x * 128, col0 = blockIdx.y * 128;
    int tr = tid >> 4, tc = tid & 15;
    float acc[8][8];
#pragma unroll
    for (int i = 0; i < 8; ++i)
#pragma unroll
        for (int j = 0; j < 8; ++j) acc[i][j] = 0.f;

    for (int kb = 0; kb < DK_; kb += 16) {
#pragma unroll
        for (int L2 = 0; L2 < 2; ++L2) {
            int f = tid + L2 * 256;
            int m = f >> 2, k4 = (f & 3) << 2;
            float4 av = *(const float4*)&x[(size_t)(row0 + m) * DK_ + kb + k4];
            As[(k4 + 0) * 132 + m] = av.x; As[(k4 + 1) * 132 + m] = av.y;
            As[(k4 + 2) * 132 + m] = av.z; As[(k4 + 3) * 132 + m] = av.w;
            float4 bv = *(const float4*)&W[(size_t)(col0 + m) * DK_ + kb + k4];
            Bs[(k4 + 0) * 132 + m] = bv.x; Bs[(k4 + 1) * 132 + m] = bv.y;
            Bs[(k4 + 2) * 132 + m] = bv.z; Bs[(k4 + 3) * 132 + m] = bv.w;
        }
        __syncthreads();
#pragma unroll
        for (int k = 0; k < 16; ++k) {
            float a[8], b[8];
#pragma unroll
            for (int i = 0; i < 8; ++i) a[i] = As[k * 132 + tr * 8 + i];
#pragma unroll
            for (int j = 0; j < 8; ++j) b[j] = Bs[k * 132 + tc * 8 + j];
#pragma unroll
            for (int i = 0; i < 8; ++i)
#pragma unroll
                for (int j = 0; j < 8; ++j) acc[i][j] = fmaf(a[i], b[j], acc[i][j]);
        }
        __syncthreads();
    }
    // epilogue: head-split layout (B,H,T,64)
#pragma unroll
    for (int i = 0; i < 8; ++i) {
        int m = row0 + tr * 8 + i;
        int b_ = m >> 12, t = m & 4095;
#pragma unroll
        for (int j = 0; j < 8; ++j) {
            int n = col0 + tc * 8 + j;
            int h = n >> 6, d = n & 63;
            C[((size_t)(b_ * H_ + h) * T_ + t) * 64 + d] = f2bf(acc[i][j]);
        }
    }
}

// ---------------------------------------------------------------------------
// Soft-hash: per key token compute 128 bucket probs (8 tables x softmax16).
// One thread per token.
// ---------------------------------------------------------------------------
__global__ __launch_bounds__(256)
void hash_kernel(const u16* __restrict__ Kb, const float* __restrict__ planes,
                 const float* __restrict__ protos, const float* __restrict__ ltemp,
                 u16* __restrict__ P)
{
    __shared__ float pl[2048];   // planes_T (64 x 32)
    __shared__ float pr[64];     // protos_T (4 x 16)
    int tid = threadIdx.x;
    for (int i = tid; i < 2048; i += 256) pl[i] = planes[i];
    if (tid < 64) pr[tid] = protos[tid];
    __syncthreads();

    float sc = __expf(ltemp[0]);
    sc = fminf(fmaxf(sc, 0.01f), 20.0f);
    float inv = 1.0f / sc;

    size_t g = (size_t)blockIdx.x * 256 + tid;   // token in [0, BH_*T_)
    const u16* kr = Kb + g * 64;

    float proj[32];
#pragma unroll
    for (int p = 0; p < 32; ++p) proj[p] = 0.f;
    for (int d = 0; d < 64; ++d) {
        float kd = bf2f(kr[d]);
#pragma unroll
        for (int p = 0; p < 32; ++p) proj[p] += kd * pl[d * 32 + p];
    }
#pragma unroll
    for (int p = 0; p < 32; ++p) {
        float e = __expf(2.f * proj[p]);           // tanh(x) = 1 - 2/(e^2x + 1)
        proj[p] = (1.f - 2.f / (e + 1.f)) * inv;
    }

    u32* orow = (u32*)(P + g * 128);
    for (int l = 0; l < 8; ++l) {
        float lg[16];
        float mx = -1e30f;
#pragma unroll
        for (int r = 0; r < 16; ++r) {
            float s = 0.f;
#pragma unroll
            for (int kbit = 0; kbit < 4; ++kbit) s += proj[l * 4 + kbit] * pr[kbit * 16 + r];
            lg[r] = s; mx = fmaxf(mx, s);
        }
        float sum = 0.f;
#pragma unroll
        for (int r = 0; r < 16; ++r) { lg[r] = __expf(lg[r] - mx); sum += lg[r]; }
        float is = 1.f / sum;
#pragma unroll
        for (int r = 0; r < 8; ++r) {
            u32 lo = f2bf(lg[2 * r] * is);
            u32 hi = f2bf(lg[2 * r + 1] * is);
            orow[l * 8 + r] = lo | (hi << 16);
        }
    }
}

// ---------------------------------------------------------------------------
// Bucket accumulation: partial[bh][chunk] = P^T @ K and P^T @ V over a
// 1024-token chunk. Grid (4 chunks, 64 bh), 256 threads.
// Thread owns (s = tid&127, d-half = tid>>7): 32+32 fp32 accumulators.
// ---------------------------------------------------------------------------
__global__ __launch_bounds__(256)
void bucket_kernel(const u16* __restrict__ P, const u16* __restrict__ Kb,
                   const u16* __restrict__ Vb, float* __restrict__ partial)
{
    __shared__ u16  Ps[128 * 128];
    __shared__ float Ksf[128 * 64];
    __shared__ float Vsf[128 * 64];
    int tid = threadIdx.x;
    int chunk = blockIdx.x, bh = blockIdx.y;
    int s = tid & 127, d0 = (tid >> 7) * 32;

    float accK[32], accV[32];
#pragma unroll
    for (int j = 0; j < 32; ++j) { accK[j] = 0.f; accV[j] = 0.f; }

    for (int sub = 0; sub < 8; ++sub) {
        int t0 = chunk * 1024 + sub * 128;
        const uint4* Pg = (const uint4*)(P + ((size_t)bh * T_ + t0) * 128);
        for (int i = tid; i < 2048; i += 256) ((uint4*)Ps)[i] = Pg[i];
        const uint4* Kg = (const uint4*)(Kb + ((size_t)bh * T_ + t0) * 64);
        const uint4* Vg = (const uint4*)(Vb + ((size_t)bh * T_ + t0) * 64);
        for (int i = tid; i < 1024; i += 256) {
            uint4 r = Kg[i];
            u32 rr[4] = { r.x, r.y, r.z, r.w };
#pragma unroll
            for (int c = 0; c < 4; ++c) {
                Ksf[i * 8 + 2 * c]     = __uint_as_float(rr[c] << 16);
                Ksf[i * 8 + 2 * c + 1] = __uint_as_float(rr[c] & 0xffff0000u);
            }
            r = Vg[i];
            u32 vv[4] = { r.x, r.y, r.z, r.w };
#pragma unroll
            for (int c = 0; c < 4; ++c) {
                Vsf[i * 8 + 2 * c]     = __uint_as_float(vv[c] << 16);
                Vsf[i * 8 + 2 * c + 1] = __uint_as_float(vv[c] & 0xffff0000u);
            }
        }
        __syncthreads();
        for (int t = 0; t < 128; ++t) {
            float p = bf2f(Ps[t * 128 + s]);
#pragma unroll
            for (int j = 0; j < 32; ++j) accK[j] = fmaf(p, Ksf[t * 64 + d0 + j], accK[j]);
#pragma unroll
            for (int j = 0; j < 32; ++j) accV[j] = fmaf(p, Vsf[t * 64 + d0 + j], accV[j]);
        }
        __syncthreads();
    }
    float* base = partial + (size_t)(bh * 4 + chunk) * 16384;
#pragma unroll
    for (int j = 0; j < 32; ++j) {
        base[s * 64 + d0 + j]        = accK[j];
        base[8192 + s * 64 + d0 + j] = accV[j];
    }
}

// Reduce 4 chunk-partials -> BKV[bh][2][128][64]
__global__ __launch_bounds__(256)
void reduce_kernel(const float* __restrict__ partial, float* __restrict__ BKV)
{
    int i = blockIdx.x * 256 + threadIdx.x;     // < 64*2*8192 = 1048576
    int bh = i >> 14; int rem = i & 16383;
    float s = 0.f;
#pragma unroll
    for (int c = 0; c < 4; ++c) s += partial[(size_t)(bh * 4 + c) * 16384 + rem];
    BKV[i] = s;
}

// ---------------------------------------------------------------------------
// Attention: per (bh, 64-token tile): scores = Q @ bK^T / 8, softmax(S=128),
// out = attn @ bV -> AO (B,T,H*64) bf16. Grid (64 tiles, 64 bh), 256 threads.
// ---------------------------------------------------------------------------
__global__ __launch_bounds__(256)
void attn_kernel(const u16* __restrict__ Qb, const float* __restrict__ BKV,
                 u16* __restrict__ AO)
{
    __shared__ float bKT[64 * 128];    // [d][s]
    __shared__ float bVs[128 * 64];    // [s][d]
    __shared__ float QsT[64 * 64];     // [d][t]
    __shared__ float Ss[64 * 129];     // [t][s], pad 129 for bank spread
    int tid = threadIdx.x;
    int bh = blockIdx.y, tt0 = blockIdx.x * 64;
    const float* bK = BKV + (size_t)bh * 16384;
    const float* bV = bK + 8192;

    for (int i = tid; i < 8192; i += 256) {
        int s = i >> 6, d = i & 63;
        bKT[d * 128 + s] = bK[i];
        bVs[i] = bV[i];
    }
    for (int i = tid; i < 4096; i += 256) {
        int t = i >> 6, d = i & 63;
        QsT[d * 64 + t] = bf2f(Qb[((size_t)bh * T_ + tt0 + t) * 64 + d]);
    }
    __syncthreads();

    int t0 = (tid >> 4) * 4, c0 = (tid & 15);
    {   // scores: each thread 4t x 8s
        int s0 = c0 * 8;
        float acc[4][8];
#pragma unroll
        for (int i = 0; i < 4; ++i)
#pragma unroll
            for (int j = 0; j < 8; ++j) acc[i][j] = 0.f;
        for (int d = 0; d < 64; ++d) {
            float q[4], b[8];
#pragma unroll
            for (int i = 0; i < 4; ++i) q[i] = QsT[d * 64 + t0 + i];
#pragma unroll
            for (int j = 0; j < 8; ++j) b[j] = bKT[d * 128 + s0 + j];
#pragma unroll
            for (int i = 0; i < 4; ++i)
#pragma unroll
                for (int j = 0; j < 8; ++j) acc[i][j] = fmaf(q[i], b[j], acc[i][j]);
        }
#pragma unroll
        for (int i = 0; i < 4; ++i)
#pragma unroll
            for (int j = 0; j < 8; ++j) Ss[(t0 + i) * 129 + s0 + j] = acc[i][j] * 0.125f;
    }
    __syncthreads();
    if (tid < 64) {   // softmax over 128 buckets, one row per thread
        float mx = -1e30f;
        for (int s2 = 0; s2 < 128; ++s2) mx = fmaxf(mx, Ss[tid * 129 + s2]);
        float sum = 0.f;
        for (int s2 = 0; s2 < 128; ++s2) {
            float e = __expf(Ss[tid * 129 + s2] - mx);
            sum += e; Ss[tid * 129 + s2] = e;
        }
        float isum = 1.f / sum;
        for (int s2 = 0; s2 < 128; ++s2) Ss[tid * 129 + s2] *= isum;
    }
    __syncthreads();
    {   // out: each thread 4t x 4d
        int d0 = c0 * 4;
        float o[4][4];
#pragma unroll
        for (int i = 0; i < 4; ++i)
#pragma unroll
            for (int j = 0; j < 4; ++j) o[i][j] = 0.f;
        for (int s2 = 0; s2 < 128; ++s2) {
            float pv[4];
#pragma unroll
            for (int i = 0; i < 4; ++i) pv[i] = Ss[(t0 + i) * 129 + s2];
            float4 vv = *(const float4*)&bVs[s2 * 64 + d0];
#pragma unroll
            for (int i = 0; i < 4; ++i) {
                o[i][0] = fmaf(pv[i], vv.x, o[i][0]);
                o[i][1] = fmaf(pv[i], vv.y, o[i][1]);
                o[i][2] = fmaf(pv[i], vv.z, o[i][2]);
                o[i][3] = fmaf(pv[i], vv.w, o[i][3]);
            }
        }
        int bb = bh >> 4, h = bh & 15;
#pragma unroll
        for (int i = 0; i < 4; ++i)
#pragma unroll
            for (int j = 0; j < 4; ++j)
                AO[((size_t)(bb * T_ + tt0 + t0 + i)) * DK_ + h * 64 + d0 + j] = f2bf(o[i][j]);
    }
}

// ---------------------------------------------------------------------------
// Output GEMM: out[m][n] = sum_k AO[m][k] * Wo[n][k] + bo[n]  (fp32 out)
// ---------------------------------------------------------------------------
__global__ __launch_bounds__(256)
void out_gemm(const u16* __restrict__ AO, const float* __restrict__ Wo,
              const float* __restrict__ bo, float* __restrict__ out)
{
    __shared__ float As[16 * 132];
    __shared__ float Bs[16 * 132];
    int tid = threadIdx.x;
    int row0 = blockIdx.x * 128, col0 = blockIdx.y * 128;
    int tr = tid >> 4, tc = tid & 15;
    float acc[8][8];
#pragma unroll
    for (int i = 0; i < 8; ++i)
#pragma unroll
        for (int j = 0; j < 8; ++j) acc[i][j] = 0.f;

    for (int kb = 0; kb < DK_; kb += 16) {
        {
            int m = tid >> 1, k8 = (tid & 1) * 8;
            uint4 r = *(const uint4*)(AO + (size_t)(row0 + m) * DK_ + kb + k8);
            u32 rr[4] = { r.x, r.y, r.z, r.w };
#pragma unroll
            for (int c = 0; c < 4; ++c) {
                As[(k8 + 2 * c) * 132 + m]     = __uint_as_float(rr[c] << 16);
                As[(k8 + 2 * c + 1) * 132 + m] = __uint_as_float(rr[c] & 0xffff0000u);
            }
        }
#pragma unroll
        for (int L2 = 0; L2 < 2; ++L2) {
            int f = tid + L2 * 256;
            int m = f >> 2, k4 = (f & 3) << 2;
            float4 bv = *(const float4*)&Wo[(size_t)(col0 + m) * DK_ + kb + k4];
            Bs[(k4 + 0) * 132 + m] = bv.x; Bs[(k4 + 1) * 132 + m] = bv.y;
            Bs[(k4 + 2) * 132 + m] = bv.z; Bs[(k4 + 3) * 132 + m] = bv.w;
        }
        __syncthreads();
#pragma unroll
        for (int k = 0; k < 16; ++k) {
            float a[8], b[8];
#pragma unroll
            for (int i = 0; i < 8; ++i) a[i] = As[k * 132 + tr * 8 + i];
#pragma unroll
            for (int j = 0; j < 8; ++j) b[j] = Bs[k * 132 + tc * 8 + j];
#pragma unroll
            for (int i = 0; i < 8; ++i)
#pragma unroll
                for (int j = 0; j < 8; ++j) acc[i][j] = fmaf(a[i], b[j], acc[i][j]);
        }
        __syncthreads();
    }
#pragma unroll
    for (int i = 0; i < 8; ++i) {
        size_t m = row0 + tr * 8 + i;
#pragma unroll
        for (int j = 0; j < 8; ++j) {
            int n = col0 + tc * 8 + j;
            out[m * DK_ + n] = acc[i][j] + bo[n];
        }
    }
}

// ---------------------------------------------------------------------------
extern "C" void kernel_launch(void* const* d_in, const int* in_sizes, int n_in,
                              void* d_out, int out_size, void* d_ws, size_t ws_size,
                              hipStream_t stream)
{
    (void)in_sizes; (void)n_in; (void)out_size; (void)ws_size;
    const float* x      = (const float*)d_in[0];
    const float* Wq     = (const float*)d_in[1];
    const float* Wk     = (const float*)d_in[2];
    const float* Wv     = (const float*)d_in[3];
    const float* Wo     = (const float*)d_in[4];
    const float* bo     = (const float*)d_in[5];
    const float* planes = (const float*)d_in[6];
    const float* protos = (const float*)d_in[7];
    const float* ltemp  = (const float*)d_in[8];
    float* out = (float*)d_out;

    char* ws = (char*)d_ws;
    size_t off = 0;
    u16* Qb = (u16*)(ws + off); off += (size_t)BH_ * T_ * 64 * 2;        // 33.5 MB
    u16* Kb = (u16*)(ws + off); off += (size_t)BH_ * T_ * 64 * 2;        // 33.5 MB
    u16* Vb = (u16*)(ws + off); off += (size_t)BH_ * T_ * 64 * 2;        // 33.5 MB
    u16* P  = (u16*)(ws + off); off += (size_t)BH_ * T_ * 128 * 2;       // 67 MB
    u16* AO = (u16*)(ws + off); off += (size_t)M_ * DK_ * 2;             // 33.5 MB
    float* partial = (float*)(ws + off); off += (size_t)BH_ * 4 * 16384 * 4; // 16.8 MB
    float* BKV     = (float*)(ws + off); off += (size_t)BH_ * 16384 * 4;     // 4.2 MB

    qkv_gemm  <<<dim3(128, 8, 3), 256, 0, stream>>>(x, Wq, Wk, Wv, Qb, Kb, Vb);
    hash_kernel<<<dim3(BH_ * T_ / 256), 256, 0, stream>>>(Kb, planes, protos, ltemp, P);
    bucket_kernel<<<dim3(4, 64), 256, 0, stream>>>(P, Kb, Vb, partial);
    reduce_kernel<<<dim3(4096), 256, 0, stream>>>(partial, BKV);
    attn_kernel<<<dim3(64, 64), 256, 0, stream>>>(Qb, BKV, AO);
    out_gemm  <<<dim3(128, 8), 256, 0, stream>>>(AO, Wo, bo, out);
}

// Round 5
// 1300.723 us; speedup vs baseline: 1.8396x; 1.8396x over previous
//
#include <hip/hip_runtime.h>
#include <hip/hip_bf16.h>
#include <math.h>

typedef unsigned short u16;
typedef unsigned int   u32;
typedef __attribute__((ext_vector_type(8))) short bf16x8;
typedef __attribute__((ext_vector_type(4))) float f32x4;

#define B_  4
#define T_  4096
#define H_  16
#define HD_ 64
#define DK_ 1024
#define S_  128
#define BH_ (B_*H_)      // 64
#define M_  (B_*T_)      // 16384

__device__ __forceinline__ float bf2f(u16 u) { return __uint_as_float(((u32)u) << 16); }
__device__ __forceinline__ u16 f2bf(float f) {
    u32 x = __float_as_uint(f);
    u32 r = (x + 0x7fffu + ((x >> 16) & 1u)) >> 16;   // round-to-nearest-even
    return (u16)r;
}

// async global->LDS, 16B per lane; lds dest must be wave-uniform (HW adds lane*16)
__device__ __forceinline__ void gld16(const void* g, void* l) {
    __builtin_amdgcn_global_load_lds((__attribute__((address_space(1))) void*)g,
                                     (__attribute__((address_space(3))) void*)l,
                                     16, 0, 0);
}

// ---------------------------------------------------------------------------
// Split fp32 -> bf16 hi + bf16 lo (x: 16384x1024)
// ---------------------------------------------------------------------------
__global__ __launch_bounds__(256)
void split_x(const float* __restrict__ x, u16* __restrict__ xhi, u16* __restrict__ xlo)
{
    const size_t n4 = (size_t)M_ * DK_ / 4;
    for (size_t i = (size_t)blockIdx.x * 256 + threadIdx.x; i < n4; i += (size_t)gridDim.x * 256) {
        float4 v = ((const float4*)x)[i];
        float vv[4] = { v.x, v.y, v.z, v.w };
        u32 hw[2], lw[2];
#pragma unroll
        for (int c = 0; c < 2; ++c) {
            u16 h0 = f2bf(vv[2*c]),   h1 = f2bf(vv[2*c+1]);
            u16 l0 = f2bf(vv[2*c]   - bf2f(h0));
            u16 l1 = f2bf(vv[2*c+1] - bf2f(h1));
            hw[c] = (u32)h0 | ((u32)h1 << 16);
            lw[c] = (u32)l0 | ((u32)l1 << 16);
        }
        ((uint2*)xhi)[i] = make_uint2(hw[0], hw[1]);
        ((uint2*)xlo)[i] = make_uint2(lw[0], lw[1]);
    }
}

// Split the 4 weight matrices (1024x1024 each). grid.z selects the weight.
__global__ __launch_bounds__(256)
void split_w(const float* __restrict__ Wq, const float* __restrict__ Wk,
             const float* __restrict__ Wv, const float* __restrict__ Wo,
             u16* __restrict__ hq, u16* __restrict__ lq,
             u16* __restrict__ hk, u16* __restrict__ lk,
             u16* __restrict__ hv, u16* __restrict__ lv,
             u16* __restrict__ ho, u16* __restrict__ lo_)
{
    int z = blockIdx.z;
    const float* W = (z == 0) ? Wq : (z == 1) ? Wk : (z == 2) ? Wv : Wo;
    u16* ph = (z == 0) ? hq : (z == 1) ? hk : (z == 2) ? hv : ho;
    u16* pl = (z == 0) ? lq : (z == 1) ? lk : (z == 2) ? lv : lo_;
    size_t i = (size_t)blockIdx.x * 256 + threadIdx.x;   // < 262144 (1M/4)
    float4 v = ((const float4*)W)[i];
    float vv[4] = { v.x, v.y, v.z, v.w };
    u32 hw[2], lw[2];
#pragma unroll
    for (int c = 0; c < 2; ++c) {
        u16 h0 = f2bf(vv[2*c]),   h1 = f2bf(vv[2*c+1]);
        u16 l0 = f2bf(vv[2*c]   - bf2f(h0));
        u16 l1 = f2bf(vv[2*c+1] - bf2f(h1));
        hw[c] = (u32)h0 | ((u32)h1 << 16);
        lw[c] = (u32)l0 | ((u32)l1 << 16);
    }
    ((uint2*)ph)[i] = make_uint2(hw[0], hw[1]);
    ((uint2*)pl)[i] = make_uint2(lw[0], lw[1]);
}

// ---------------------------------------------------------------------------
// QKV MFMA GEMM: C[m][n] = sum over effective K=3072 of A''·B'' where
//  A'' = [xhi | xlo | xhi], B'' = [whi | whi | wlo]   (split-fp32 trick)
// 128x128 tile, 4 waves, 4x4 16x16x32 frags/wave, BK=64, global_load_lds.
// Epilogue -> bf16 (B,H,T,64). blockIdx.z picks Q/K/V.
// ---------------------------------------------------------------------------
__global__ __launch_bounds__(256)
void qkv_mfma(const u16* __restrict__ xhi, const u16* __restrict__ xlo,
              const u16* __restrict__ hq, const u16* __restrict__ lq,
              const u16* __restrict__ hk, const u16* __restrict__ lk,
              const u16* __restrict__ hv, const u16* __restrict__ lv,
              u16* __restrict__ Qb, u16* __restrict__ Kb, u16* __restrict__ Vb)
{
    __shared__ u16 At[128 * 64];
    __shared__ u16 Bt[128 * 64];
    int z = blockIdx.z;
    const u16* whi = (z == 0) ? hq : (z == 1) ? hk : hv;
    const u16* wlo = (z == 0) ? lq : (z == 1) ? lk : lv;
    u16* C = (z == 0) ? Qb : (z == 1) ? Kb : Vb;

    int tid = threadIdx.x, l = tid & 63, w = tid >> 6;
    int row0 = blockIdx.x * 128, col0 = blockIdx.y * 128;
    int wr = (w >> 1) * 64, wc = (w & 1) * 64;
    int srow = l >> 3, scolb = (l & 7) * 16;      // staging: row-in-chunk, byte col
    int lane15 = l & 15, lhalf = l >> 4;

    f32x4 acc[4][4];
#pragma unroll
    for (int i = 0; i < 4; ++i)
#pragma unroll
        for (int j = 0; j < 4; ++j) acc[i][j] = (f32x4){0.f, 0.f, 0.f, 0.f};

    int aoff[4], boff[4];
#pragma unroll
    for (int f = 0; f < 4; ++f) {
        aoff[f] = (wr + f * 16 + lane15) * 64 + lhalf * 8;
        boff[f] = (wc + f * 16 + lane15) * 64 + lhalf * 8;
    }

    for (int kb = 0; kb < 3072; kb += 64) {
        int seg = kb >> 10, kc = kb & 1023;
        const u16* Asrc = (seg == 1) ? xlo : xhi;
        const u16* Bsrc = (seg == 2) ? wlo : whi;
#pragma unroll
        for (int i2 = 0; i2 < 4; ++i2) {
            int c = w * 4 + i2;                    // chunk: 8 rows x 64 cols = 1KB
            gld16((const char*)(Asrc + (size_t)(row0 + c * 8 + srow) * 1024 + kc) + scolb,
                  (char*)At + c * 1024);
            gld16((const char*)(Bsrc + (size_t)(col0 + c * 8 + srow) * 1024 + kc) + scolb,
                  (char*)Bt + c * 1024);
        }
        __syncthreads();
#pragma unroll
        for (int ks = 0; ks < 2; ++ks) {
            bf16x8 a[4], b[4];
#pragma unroll
            for (int f = 0; f < 4; ++f) a[f] = *(const bf16x8*)&At[aoff[f] + ks * 32];
#pragma unroll
            for (int f = 0; f < 4; ++f) b[f] = *(const bf16x8*)&Bt[boff[f] + ks * 32];
#pragma unroll
            for (int fi = 0; fi < 4; ++fi)
#pragma unroll
                for (int fj = 0; fj < 4; ++fj)
                    acc[fi][fj] = __builtin_amdgcn_mfma_f32_16x16x32_bf16(a[fi], b[fj], acc[fi][fj], 0, 0, 0);
        }
        __syncthreads();
    }
    // epilogue: C/D frag: col = lane&15, row = (lane>>4)*4 + reg  [m89]
#pragma unroll
    for (int fi = 0; fi < 4; ++fi) {
#pragma unroll
        for (int j = 0; j < 4; ++j) {
            int m = row0 + wr + fi * 16 + lhalf * 4 + j;
            int b_ = m >> 12, t = m & 4095;
#pragma unroll
            for (int fj = 0; fj < 4; ++fj) {
                int n = col0 + wc + fj * 16 + lane15;
                int h = n >> 6, d = n & 63;
                C[((size_t)(b_ * H_ + h) * T_ + t) * 64 + d] = f2bf(acc[fi][fj][j]);
            }
        }
    }
}

// ---------------------------------------------------------------------------
// Output MFMA GEMM: out = AO(bf16) @ [Wohi | Wolo]^T + bo, K=2048, fp32 out.
// ---------------------------------------------------------------------------
__global__ __launch_bounds__(256)
void out_mfma(const u16* __restrict__ AO, const u16* __restrict__ wohi,
              const u16* __restrict__ wolo, const float* __restrict__ bo,
              float* __restrict__ out)
{
    __shared__ u16 At[128 * 64];
    __shared__ u16 Bt[128 * 64];
    int tid = threadIdx.x, l = tid & 63, w = tid >> 6;
    int row0 = blockIdx.x * 128, col0 = blockIdx.y * 128;
    int wr = (w >> 1) * 64, wc = (w & 1) * 64;
    int srow = l >> 3, scolb = (l & 7) * 16;
    int lane15 = l & 15, lhalf = l >> 4;

    f32x4 acc[4][4];
#pragma unroll
    for (int i = 0; i < 4; ++i)
#pragma unroll
        for (int j = 0; j < 4; ++j) acc[i][j] = (f32x4){0.f, 0.f, 0.f, 0.f};

    int aoff[4], boff[4];
#pragma unroll
    for (int f = 0; f < 4; ++f) {
        aoff[f] = (wr + f * 16 + lane15) * 64 + lhalf * 8;
        boff[f] = (wc + f * 16 + lane15) * 64 + lhalf * 8;
    }

    for (int kb = 0; kb < 2048; kb += 64) {
        int seg = kb >> 10, kc = kb & 1023;
        const u16* Bsrc = seg ? wolo : wohi;
#pragma unroll
        for (int i2 = 0; i2 < 4; ++i2) {
            int c = w * 4 + i2;
            gld16((const char*)(AO + (size_t)(row0 + c * 8 + srow) * 1024 + kc) + scolb,
                  (char*)At + c * 1024);
            gld16((const char*)(Bsrc + (size_t)(col0 + c * 8 + srow) * 1024 + kc) + scolb,
                  (char*)Bt + c * 1024);
        }
        __syncthreads();
#pragma unroll
        for (int ks = 0; ks < 2; ++ks) {
            bf16x8 a[4], b[4];
#pragma unroll
            for (int f = 0; f < 4; ++f) a[f] = *(const bf16x8*)&At[aoff[f] + ks * 32];
#pragma unroll
            for (int f = 0; f < 4; ++f) b[f] = *(const bf16x8*)&Bt[boff[f] + ks * 32];
#pragma unroll
            for (int fi = 0; fi < 4; ++fi)
#pragma unroll
                for (int fj = 0; fj < 4; ++fj)
                    acc[fi][fj] = __builtin_amdgcn_mfma_f32_16x16x32_bf16(a[fi], b[fj], acc[fi][fj], 0, 0, 0);
        }
        __syncthreads();
    }
#pragma unroll
    for (int fi = 0; fi < 4; ++fi) {
#pragma unroll
        for (int j = 0; j < 4; ++j) {
            size_t m = row0 + wr + fi * 16 + lhalf * 4 + j;
#pragma unroll
            for (int fj = 0; fj < 4; ++fj) {
                int n = col0 + wc + fj * 16 + lane15;
                out[m * DK_ + n] = acc[fi][fj][j] + bo[n];
            }
        }
    }
}

// ---------------------------------------------------------------------------
// Soft-hash (unchanged): per key token 128 bucket probs (8 tables x softmax16)
// ---------------------------------------------------------------------------
__global__ __launch_bounds__(256)
void hash_kernel(const u16* __restrict__ Kb, const float* __restrict__ planes,
                 const float* __restrict__ protos, const float* __restrict__ ltemp,
                 u16* __restrict__ P)
{
    __shared__ float pl[2048];
    __shared__ float pr[64];
    int tid = threadIdx.x;
    for (int i = tid; i < 2048; i += 256) pl[i] = planes[i];
    if (tid < 64) pr[tid] = protos[tid];
    __syncthreads();

    float sc = __expf(ltemp[0]);
    sc = fminf(fmaxf(sc, 0.01f), 20.0f);
    float inv = 1.0f / sc;

    size_t g = (size_t)blockIdx.x * 256 + tid;
    const u16* kr = Kb + g * 64;

    float proj[32];
#pragma unroll
    for (int p = 0; p < 32; ++p) proj[p] = 0.f;
    for (int d = 0; d < 64; ++d) {
        float kd = bf2f(kr[d]);
#pragma unroll
        for (int p = 0; p < 32; ++p) proj[p] += kd * pl[d * 32 + p];
    }
#pragma unroll
    for (int p = 0; p < 32; ++p) {
        float e = __expf(2.f * proj[p]);
        proj[p] = (1.f - 2.f / (e + 1.f)) * inv;
    }

    u32* orow = (u32*)(P + g * 128);
    for (int l = 0; l < 8; ++l) {
        float lg[16];
        float mx = -1e30f;
#pragma unroll
        for (int r = 0; r < 16; ++r) {
            float s = 0.f;
#pragma unroll
            for (int kbit = 0; kbit < 4; ++kbit) s += proj[l * 4 + kbit] * pr[kbit * 16 + r];
            lg[r] = s; mx = fmaxf(mx, s);
        }
        float sum = 0.f;
#pragma unroll
        for (int r = 0; r < 16; ++r) { lg[r] = __expf(lg[r] - mx); sum += lg[r]; }
        float is = 1.f / sum;
#pragma unroll
        for (int r = 0; r < 8; ++r) {
            u32 lo = f2bf(lg[2 * r] * is);
            u32 hi = f2bf(lg[2 * r + 1] * is);
            orow[l * 8 + r] = lo | (hi << 16);
        }
    }
}

// ---------------------------------------------------------------------------
// Bucket accumulation (unchanged)
// ---------------------------------------------------------------------------
__global__ __launch_bounds__(256)
void bucket_kernel(const u16* __restrict__ P, const u16* __restrict__ Kb,
                   const u16* __restrict__ Vb, float* __restrict__ partial)
{
    __shared__ u16  Ps[128 * 128];
    __shared__ float Ksf[128 * 64];
    __shared__ float Vsf[128 * 64];
    int tid = threadIdx.x;
    int chunk = blockIdx.x, bh = blockIdx.y;
    int s = tid & 127, d0 = (tid >> 7) * 32;

    float accK[32], accV[32];
#pragma unroll
    for (int j = 0; j < 32; ++j) { accK[j] = 0.f; accV[j] = 0.f; }

    for (int sub = 0; sub < 8; ++sub) {
        int t0 = chunk * 1024 + sub * 128;
        const uint4* Pg = (const uint4*)(P + ((size_t)bh * T_ + t0) * 128);
        for (int i = tid; i < 2048; i += 256) ((uint4*)Ps)[i] = Pg[i];
        const uint4* Kg = (const uint4*)(Kb + ((size_t)bh * T_ + t0) * 64);
        const uint4* Vg = (const uint4*)(Vb + ((size_t)bh * T_ + t0) * 64);
        for (int i = tid; i < 1024; i += 256) {
            uint4 r = Kg[i];
            u32 rr[4] = { r.x, r.y, r.z, r.w };
#pragma unroll
            for (int c = 0; c < 4; ++c) {
                Ksf[i * 8 + 2 * c]     = __uint_as_float(rr[c] << 16);
                Ksf[i * 8 + 2 * c + 1] = __uint_as_float(rr[c] & 0xffff0000u);
            }
            r = Vg[i];
            u32 vv[4] = { r.x, r.y, r.z, r.w };
#pragma unroll
            for (int c = 0; c < 4; ++c) {
                Vsf[i * 8 + 2 * c]     = __uint_as_float(vv[c] << 16);
                Vsf[i * 8 + 2 * c + 1] = __uint_as_float(vv[c] & 0xffff0000u);
            }
        }
        __syncthreads();
        for (int t = 0; t < 128; ++t) {
            float p = bf2f(Ps[t * 128 + s]);
#pragma unroll
            for (int j = 0; j < 32; ++j) accK[j] = fmaf(p, Ksf[t * 64 + d0 + j], accK[j]);
#pragma unroll
            for (int j = 0; j < 32; ++j) accV[j] = fmaf(p, Vsf[t * 64 + d0 + j], accV[j]);
        }
        __syncthreads();
    }
    float* base = partial + (size_t)(bh * 4 + chunk) * 16384;
#pragma unroll
    for (int j = 0; j < 32; ++j) {
        base[s * 64 + d0 + j]        = accK[j];
        base[8192 + s * 64 + d0 + j] = accV[j];
    }
}

__global__ __launch_bounds__(256)
void reduce_kernel(const float* __restrict__ partial, float* __restrict__ BKV)
{
    int i = blockIdx.x * 256 + threadIdx.x;
    int bh = i >> 14; int rem = i & 16383;
    float s = 0.f;
#pragma unroll
    for (int c = 0; c < 4; ++c) s += partial[(size_t)(bh * 4 + c) * 16384 + rem];
    BKV[i] = s;
}

// ---------------------------------------------------------------------------
// Attention (unchanged)
// ---------------------------------------------------------------------------
__global__ __launch_bounds__(256)
void attn_kernel(const u16* __restrict__ Qb, const float* __restrict__ BKV,
                 u16* __restrict__ AO)
{
    __shared__ float bKT[64 * 128];
    __shared__ float bVs[128 * 64];
    __shared__ float QsT[64 * 64];
    __shared__ float Ss[64 * 129];
    int tid = threadIdx.x;
    int bh = blockIdx.y, tt0 = blockIdx.x * 64;
    const float* bK = BKV + (size_t)bh * 16384;
    const float* bV = bK + 8192;

    for (int i = tid; i < 8192; i += 256) {
        int s = i >> 6, d = i & 63;
        bKT[d * 128 + s] = bK[i];
        bVs[i] = bV[i];
    }
    for (int i = tid; i < 4096; i += 256) {
        int t = i >> 6, d = i & 63;
        QsT[d * 64 + t] = bf2f(Qb[((size_t)bh * T_ + tt0 + t) * 64 + d]);
    }
    __syncthreads();

    int t0 = (tid >> 4) * 4, c0 = (tid & 15);
    {
        int s0 = c0 * 8;
        float acc[4][8];
#pragma unroll
        for (int i = 0; i < 4; ++i)
#pragma unroll
            for (int j = 0; j < 8; ++j) acc[i][j] = 0.f;
        for (int d = 0; d < 64; ++d) {
            float q[4], b[8];
#pragma unroll
            for (int i = 0; i < 4; ++i) q[i] = QsT[d * 64 + t0 + i];
#pragma unroll
            for (int j = 0; j < 8; ++j) b[j] = bKT[d * 128 + s0 + j];
#pragma unroll
            for (int i = 0; i < 4; ++i)
#pragma unroll
                for (int j = 0; j < 8; ++j) acc[i][j] = fmaf(q[i], b[j], acc[i][j]);
        }
#pragma unroll
        for (int i = 0; i < 4; ++i)
#pragma unroll
            for (int j = 0; j < 8; ++j) Ss[(t0 + i) * 129 + s0 + j] = acc[i][j] * 0.125f;
    }
    __syncthreads();
    if (tid < 64) {
        float mx = -1e30f;
        for (int s2 = 0; s2 < 128; ++s2) mx = fmaxf(mx, Ss[tid * 129 + s2]);
        float sum = 0.f;
        for (int s2 = 0; s2 < 128; ++s2) {
            float e = __expf(Ss[tid * 129 + s2] - mx);
            sum += e; Ss[tid * 129 + s2] = e;
        }
        float isum = 1.f / sum;
        for (int s2 = 0; s2 < 128; ++s2) Ss[tid * 129 + s2] *= isum;
    }
    __syncthreads();
    {
        int d0 = c0 * 4;
        float o[4][4];
#pragma unroll
        for (int i = 0; i < 4; ++i)
#pragma unroll
            for (int j = 0; j < 4; ++j) o[i][j] = 0.f;
        for (int s2 = 0; s2 < 128; ++s2) {
            float pv[4];
#pragma unroll
            for (int i = 0; i < 4; ++i) pv[i] = Ss[(t0 + i) * 129 + s2];
            float4 vv = *(const float4*)&bVs[s2 * 64 + d0];
#pragma unroll
            for (int i = 0; i < 4; ++i) {
                o[i][0] = fmaf(pv[i], vv.x, o[i][0]);
                o[i][1] = fmaf(pv[i], vv.y, o[i][1]);
                o[i][2] = fmaf(pv[i], vv.z, o[i][2]);
                o[i][3] = fmaf(pv[i], vv.w, o[i][3]);
            }
        }
        int bb = bh >> 4, h = bh & 15;
#pragma unroll
        for (int i = 0; i < 4; ++i)
#pragma unroll
            for (int j = 0; j < 4; ++j)
                AO[((size_t)(bb * T_ + tt0 + t0 + i)) * DK_ + h * 64 + d0 + j] = f2bf(o[i][j]);
    }
}

// ---------------------------------------------------------------------------
extern "C" void kernel_launch(void* const* d_in, const int* in_sizes, int n_in,
                              void* d_out, int out_size, void* d_ws, size_t ws_size,
                              hipStream_t stream)
{
    (void)in_sizes; (void)n_in; (void)out_size; (void)ws_size;
    const float* x      = (const float*)d_in[0];
    const float* Wq     = (const float*)d_in[1];
    const float* Wk     = (const float*)d_in[2];
    const float* Wv     = (const float*)d_in[3];
    const float* Wo     = (const float*)d_in[4];
    const float* bo     = (const float*)d_in[5];
    const float* planes = (const float*)d_in[6];
    const float* protos = (const float*)d_in[7];
    const float* ltemp  = (const float*)d_in[8];
    float* out = (float*)d_out;

    char* ws = (char*)d_ws;
    // Region A (splits of x and Wq/Wk/Wv; dead after qkv_mfma) — P aliases it.
    u16* xhi = (u16*)(ws);                         // 33.5 MB
    u16* xlo = (u16*)(ws + 33554432ull);           // 33.5 MB
    u16* hq  = (u16*)(ws + 67108864ull);
    u16* lq  = (u16*)(ws + 69206016ull);
    u16* hk  = (u16*)(ws + 71303168ull);
    u16* lk  = (u16*)(ws + 73400320ull);
    u16* hv  = (u16*)(ws + 75497472ull);
    u16* lv  = (u16*)(ws + 77594624ull);           // region A ends at 79,691,776
    u16* P   = (u16*)(ws);                         // 67.1 MB, aliases region A (hash runs after qkv)
    size_t off = 79691776ull;
    u16* Qb = (u16*)(ws + off); off += 33554432ull;
    u16* Kb = (u16*)(ws + off); off += 33554432ull;
    u16* Vb = (u16*)(ws + off); off += 33554432ull;
    u16* wohi = (u16*)(ws + off); off += 2097152ull;
    u16* wolo = (u16*)(ws + off); off += 2097152ull;
    // AO aliases partial (partial dead before attn writes AO)
    float* partial = (float*)(ws + off);
    u16*   AO      = (u16*)(ws + off); off += 33554432ull;
    float* BKV     = (float*)(ws + off); off += 4194304ull;   // total ~216.5 MB

    split_x<<<dim3(4096), 256, 0, stream>>>(x, xhi, xlo);
    split_w<<<dim3(1024, 1, 4), 256, 0, stream>>>(Wq, Wk, Wv, Wo, hq, lq, hk, lk, hv, lv, wohi, wolo);
    qkv_mfma<<<dim3(128, 8, 3), 256, 0, stream>>>(xhi, xlo, hq, lq, hk, lk, hv, lv, Qb, Kb, Vb);
    hash_kernel<<<dim3(BH_ * T_ / 256), 256, 0, stream>>>(Kb, planes, protos, ltemp, P);
    bucket_kernel<<<dim3(4, 64), 256, 0, stream>>>(P, Kb, Vb, partial);
    reduce_kernel<<<dim3(4096), 256, 0, stream>>>(partial, BKV);
    attn_kernel<<<dim3(64, 64), 256, 0, stream>>>(Qb, BKV, AO);
    out_mfma<<<dim3(128, 8), 256, 0, stream>>>(AO, wohi, wolo, bo, out);
}

// Round 6
// 1170.928 us; speedup vs baseline: 2.0435x; 1.1108x over previous
//
#include <hip/hip_runtime.h>
#include <hip/hip_bf16.h>
#include <math.h>

typedef unsigned short u16;
typedef unsigned int   u32;
typedef __attribute__((ext_vector_type(8))) short bf16x8;
typedef __attribute__((ext_vector_type(4))) float f32x4;

#define B_  4
#define T_  4096
#define H_  16
#define HD_ 64
#define DK_ 1024
#define S_  128
#define BH_ (B_*H_)      // 64
#define M_  (B_*T_)      // 16384

__device__ __forceinline__ float bf2f(u16 u) { return __uint_as_float(((u32)u) << 16); }
__device__ __forceinline__ u16 f2bf(float f) {
    u32 x = __float_as_uint(f);
    u32 r = (x + 0x7fffu + ((x >> 16) & 1u)) >> 16;   // round-to-nearest-even
    return (u16)r;
}

// async global->LDS, 16B per lane; lds dest must be wave-uniform (HW adds lane*16)
__device__ __forceinline__ void gld16(const void* g, void* l) {
    __builtin_amdgcn_global_load_lds((__attribute__((address_space(1))) void*)g,
                                     (__attribute__((address_space(3))) void*)l,
                                     16, 0, 0);
}

// ---------------------------------------------------------------------------
// Split fp32 -> bf16 hi + bf16 lo (x: 16384x1024)
// ---------------------------------------------------------------------------
__global__ __launch_bounds__(256)
void split_x(const float* __restrict__ x, u16* __restrict__ xhi, u16* __restrict__ xlo)
{
    const size_t n4 = (size_t)M_ * DK_ / 4;
    for (size_t i = (size_t)blockIdx.x * 256 + threadIdx.x; i < n4; i += (size_t)gridDim.x * 256) {
        float4 v = ((const float4*)x)[i];
        float vv[4] = { v.x, v.y, v.z, v.w };
        u32 hw[2], lw[2];
#pragma unroll
        for (int c = 0; c < 2; ++c) {
            u16 h0 = f2bf(vv[2*c]),   h1 = f2bf(vv[2*c+1]);
            u16 l0 = f2bf(vv[2*c]   - bf2f(h0));
            u16 l1 = f2bf(vv[2*c+1] - bf2f(h1));
            hw[c] = (u32)h0 | ((u32)h1 << 16);
            lw[c] = (u32)l0 | ((u32)l1 << 16);
        }
        ((uint2*)xhi)[i] = make_uint2(hw[0], hw[1]);
        ((uint2*)xlo)[i] = make_uint2(lw[0], lw[1]);
    }
}

// Split the 4 weight matrices (1024x1024 each). grid.z selects the weight.
__global__ __launch_bounds__(256)
void split_w(const float* __restrict__ Wq, const float* __restrict__ Wk,
             const float* __restrict__ Wv, const float* __restrict__ Wo,
             u16* __restrict__ hq, u16* __restrict__ lq,
             u16* __restrict__ hk, u16* __restrict__ lk,
             u16* __restrict__ hv, u16* __restrict__ lv,
             u16* __restrict__ ho, u16* __restrict__ lo_)
{
    int z = blockIdx.z;
    const float* W = (z == 0) ? Wq : (z == 1) ? Wk : (z == 2) ? Wv : Wo;
    u16* ph = (z == 0) ? hq : (z == 1) ? hk : (z == 2) ? hv : ho;
    u16* pl = (z == 0) ? lq : (z == 1) ? lk : (z == 2) ? lv : lo_;
    size_t i = (size_t)blockIdx.x * 256 + threadIdx.x;   // < 262144 (1M/4)
    float4 v = ((const float4*)W)[i];
    float vv[4] = { v.x, v.y, v.z, v.w };
    u32 hw[2], lw[2];
#pragma unroll
    for (int c = 0; c < 2; ++c) {
        u16 h0 = f2bf(vv[2*c]),   h1 = f2bf(vv[2*c+1]);
        u16 l0 = f2bf(vv[2*c]   - bf2f(h0));
        u16 l1 = f2bf(vv[2*c+1] - bf2f(h1));
        hw[c] = (u32)h0 | ((u32)h1 << 16);
        lw[c] = (u32)l0 | ((u32)l1 << 16);
    }
    ((uint2*)ph)[i] = make_uint2(hw[0], hw[1]);
    ((uint2*)pl)[i] = make_uint2(lw[0], lw[1]);
}

// ---------------------------------------------------------------------------
// QKV MFMA GEMM: C[m][n] = sum over effective K=3072 of A''·B'' where
//  A'' = [xhi | xlo | xhi], B'' = [whi | whi | wlo]   (split-fp32 trick)
// 128x128 tile, 4 waves, 4x4 16x16x32 frags/wave, BK=64, global_load_lds.
// T2 XOR-swizzle: LDS linear, SOURCE col pre-swizzled (lane), reads XOR'd
//   involution: elem_off ^= (row&7)<<3  (16B granule within 128B row).
// Epilogue -> bf16 (B,H,T,64). blockIdx.z picks Q/K/V.
// ---------------------------------------------------------------------------
__global__ __launch_bounds__(256)
void qkv_mfma(const u16* __restrict__ xhi, const u16* __restrict__ xlo,
              const u16* __restrict__ hq, const u16* __restrict__ lq,
              const u16* __restrict__ hk, const u16* __restrict__ lk,
              const u16* __restrict__ hv, const u16* __restrict__ lv,
              u16* __restrict__ Qb, u16* __restrict__ Kb, u16* __restrict__ Vb)
{
    __shared__ u16 At[128 * 64];
    __shared__ u16 Bt[128 * 64];
    int z = blockIdx.z;
    const u16* whi = (z == 0) ? hq : (z == 1) ? hk : hv;
    const u16* wlo = (z == 0) ? lq : (z == 1) ? lk : lv;
    u16* C = (z == 0) ? Qb : (z == 1) ? Kb : Vb;

    int tid = threadIdx.x, l = tid & 63, w = tid >> 6;
    int row0 = blockIdx.x * 128, col0 = blockIdx.y * 128;
    int wr = (w >> 1) * 64, wc = (w & 1) * 64;
    int srow = l >> 3;                          // row within 8-row chunk
    int scol = ((l & 7) ^ srow) << 3;           // pre-swizzled source col (elems)
    int lane15 = l & 15, lhalf = l >> 4;

    f32x4 acc[4][4];
#pragma unroll
    for (int i = 0; i < 4; ++i)
#pragma unroll
        for (int j = 0; j < 4; ++j) acc[i][j] = (f32x4){0.f, 0.f, 0.f, 0.f};

    int aoff[4][2], boff[4][2];
#pragma unroll
    for (int f = 0; f < 4; ++f) {
#pragma unroll
        for (int ks = 0; ks < 2; ++ks) {
            int sw = (lane15 & 7) << 3;
            aoff[f][ks] = (wr + f * 16 + lane15) * 64 + ((lhalf * 8 + ks * 32) ^ sw);
            boff[f][ks] = (wc + f * 16 + lane15) * 64 + ((lhalf * 8 + ks * 32) ^ sw);
        }
    }

    for (int kb = 0; kb < 3072; kb += 64) {
        int seg = kb >> 10, kc = kb & 1023;
        const u16* Asrc = (seg == 1) ? xlo : xhi;
        const u16* Bsrc = (seg == 2) ? wlo : whi;
#pragma unroll
        for (int i2 = 0; i2 < 4; ++i2) {
            int c = w * 4 + i2;                    // chunk: 8 rows x 64 cols = 1KB
            gld16(Asrc + (size_t)(row0 + c * 8 + srow) * 1024 + kc + scol,
                  (char*)At + c * 1024);
            gld16(Bsrc + (size_t)(col0 + c * 8 + srow) * 1024 + kc + scol,
                  (char*)Bt + c * 1024);
        }
        __syncthreads();
#pragma unroll
        for (int ks = 0; ks < 2; ++ks) {
            bf16x8 a[4], b[4];
#pragma unroll
            for (int f = 0; f < 4; ++f) a[f] = *(const bf16x8*)&At[aoff[f][ks]];
#pragma unroll
            for (int f = 0; f < 4; ++f) b[f] = *(const bf16x8*)&Bt[boff[f][ks]];
#pragma unroll
            for (int fi = 0; fi < 4; ++fi)
#pragma unroll
                for (int fj = 0; fj < 4; ++fj)
                    acc[fi][fj] = __builtin_amdgcn_mfma_f32_16x16x32_bf16(a[fi], b[fj], acc[fi][fj], 0, 0, 0);
        }
        __syncthreads();
    }
    // epilogue: C/D frag: col = lane&15, row = (lane>>4)*4 + reg  [m89]
#pragma unroll
    for (int fi = 0; fi < 4; ++fi) {
#pragma unroll
        for (int j = 0; j < 4; ++j) {
            int m = row0 + wr + fi * 16 + lhalf * 4 + j;
            int b_ = m >> 12, t = m & 4095;
#pragma unroll
            for (int fj = 0; fj < 4; ++fj) {
                int n = col0 + wc + fj * 16 + lane15;
                int h = n >> 6, d = n & 63;
                C[((size_t)(b_ * H_ + h) * T_ + t) * 64 + d] = f2bf(acc[fi][fj][j]);
            }
        }
    }
}

// ---------------------------------------------------------------------------
// Output MFMA GEMM: out = AO(bf16) @ [Wohi | Wolo]^T + bo, K=2048, fp32 out.
// Same T2 swizzle as qkv_mfma.
// ---------------------------------------------------------------------------
__global__ __launch_bounds__(256)
void out_mfma(const u16* __restrict__ AO, const u16* __restrict__ wohi,
              const u16* __restrict__ wolo, const float* __restrict__ bo,
              float* __restrict__ out)
{
    __shared__ u16 At[128 * 64];
    __shared__ u16 Bt[128 * 64];
    int tid = threadIdx.x, l = tid & 63, w = tid >> 6;
    int row0 = blockIdx.x * 128, col0 = blockIdx.y * 128;
    int wr = (w >> 1) * 64, wc = (w & 1) * 64;
    int srow = l >> 3;
    int scol = ((l & 7) ^ srow) << 3;
    int lane15 = l & 15, lhalf = l >> 4;

    f32x4 acc[4][4];
#pragma unroll
    for (int i = 0; i < 4; ++i)
#pragma unroll
        for (int j = 0; j < 4; ++j) acc[i][j] = (f32x4){0.f, 0.f, 0.f, 0.f};

    int aoff[4][2], boff[4][2];
#pragma unroll
    for (int f = 0; f < 4; ++f) {
#pragma unroll
        for (int ks = 0; ks < 2; ++ks) {
            int sw = (lane15 & 7) << 3;
            aoff[f][ks] = (wr + f * 16 + lane15) * 64 + ((lhalf * 8 + ks * 32) ^ sw);
            boff[f][ks] = (wc + f * 16 + lane15) * 64 + ((lhalf * 8 + ks * 32) ^ sw);
        }
    }

    for (int kb = 0; kb < 2048; kb += 64) {
        int seg = kb >> 10, kc = kb & 1023;
        const u16* Bsrc = seg ? wolo : wohi;
#pragma unroll
        for (int i2 = 0; i2 < 4; ++i2) {
            int c = w * 4 + i2;
            gld16(AO + (size_t)(row0 + c * 8 + srow) * 1024 + kc + scol,
                  (char*)At + c * 1024);
            gld16(Bsrc + (size_t)(col0 + c * 8 + srow) * 1024 + kc + scol,
                  (char*)Bt + c * 1024);
        }
        __syncthreads();
#pragma unroll
        for (int ks = 0; ks < 2; ++ks) {
            bf16x8 a[4], b[4];
#pragma unroll
            for (int f = 0; f < 4; ++f) a[f] = *(const bf16x8*)&At[aoff[f][ks]];
#pragma unroll
            for (int f = 0; f < 4; ++f) b[f] = *(const bf16x8*)&Bt[boff[f][ks]];
#pragma unroll
            for (int fi = 0; fi < 4; ++fi)
#pragma unroll
                for (int fj = 0; fj < 4; ++fj)
                    acc[fi][fj] = __builtin_amdgcn_mfma_f32_16x16x32_bf16(a[fi], b[fj], acc[fi][fj], 0, 0, 0);
        }
        __syncthreads();
    }
#pragma unroll
    for (int fi = 0; fi < 4; ++fi) {
#pragma unroll
        for (int j = 0; j < 4; ++j) {
            size_t m = row0 + wr + fi * 16 + lhalf * 4 + j;
#pragma unroll
            for (int fj = 0; fj < 4; ++fj) {
                int n = col0 + wc + fj * 16 + lane15;
                out[m * DK_ + n] = acc[fi][fj][j] + bo[n];
            }
        }
    }
}

// ---------------------------------------------------------------------------
// Soft-hash (unchanged): per key token 128 bucket probs (8 tables x softmax16)
// ---------------------------------------------------------------------------
__global__ __launch_bounds__(256)
void hash_kernel(const u16* __restrict__ Kb, const float* __restrict__ planes,
                 const float* __restrict__ protos, const float* __restrict__ ltemp,
                 u16* __restrict__ P)
{
    __shared__ float pl[2048];
    __shared__ float pr[64];
    int tid = threadIdx.x;
    for (int i = tid; i < 2048; i += 256) pl[i] = planes[i];
    if (tid < 64) pr[tid] = protos[tid];
    __syncthreads();

    float sc = __expf(ltemp[0]);
    sc = fminf(fmaxf(sc, 0.01f), 20.0f);
    float inv = 1.0f / sc;

    size_t g = (size_t)blockIdx.x * 256 + tid;
    const u16* kr = Kb + g * 64;

    float proj[32];
#pragma unroll
    for (int p = 0; p < 32; ++p) proj[p] = 0.f;
    for (int d = 0; d < 64; ++d) {
        float kd = bf2f(kr[d]);
#pragma unroll
        for (int p = 0; p < 32; ++p) proj[p] += kd * pl[d * 32 + p];
    }
#pragma unroll
    for (int p = 0; p < 32; ++p) {
        float e = __expf(2.f * proj[p]);
        proj[p] = (1.f - 2.f / (e + 1.f)) * inv;
    }

    u32* orow = (u32*)(P + g * 128);
    for (int l = 0; l < 8; ++l) {
        float lg[16];
        float mx = -1e30f;
#pragma unroll
        for (int r = 0; r < 16; ++r) {
            float s = 0.f;
#pragma unroll
            for (int kbit = 0; kbit < 4; ++kbit) s += proj[l * 4 + kbit] * pr[kbit * 16 + r];
            lg[r] = s; mx = fmaxf(mx, s);
        }
        float sum = 0.f;
#pragma unroll
        for (int r = 0; r < 16; ++r) { lg[r] = __expf(lg[r] - mx); sum += lg[r]; }
        float is = 1.f / sum;
#pragma unroll
        for (int r = 0; r < 8; ++r) {
            u32 lo = f2bf(lg[2 * r] * is);
            u32 hi = f2bf(lg[2 * r + 1] * is);
            orow[l * 8 + r] = lo | (hi << 16);
        }
    }
}

// ---------------------------------------------------------------------------
// Bucket accumulation (unchanged)
// ---------------------------------------------------------------------------
__global__ __launch_bounds__(256)
void bucket_kernel(const u16* __restrict__ P, const u16* __restrict__ Kb,
                   const u16* __restrict__ Vb, float* __restrict__ partial)
{
    __shared__ u16  Ps[128 * 128];
    __shared__ float Ksf[128 * 64];
    __shared__ float Vsf[128 * 64];
    int tid = threadIdx.x;
    int chunk = blockIdx.x, bh = blockIdx.y;
    int s = tid & 127, d0 = (tid >> 7) * 32;

    float accK[32], accV[32];
#pragma unroll
    for (int j = 0; j < 32; ++j) { accK[j] = 0.f; accV[j] = 0.f; }

    for (int sub = 0; sub < 8; ++sub) {
        int t0 = chunk * 1024 + sub * 128;
        const uint4* Pg = (const uint4*)(P + ((size_t)bh * T_ + t0) * 128);
        for (int i = tid; i < 2048; i += 256) ((uint4*)Ps)[i] = Pg[i];
        const uint4* Kg = (const uint4*)(Kb + ((size_t)bh * T_ + t0) * 64);
        const uint4* Vg = (const uint4*)(Vb + ((size_t)bh * T_ + t0) * 64);
        for (int i = tid; i < 1024; i += 256) {
            uint4 r = Kg[i];
            u32 rr[4] = { r.x, r.y, r.z, r.w };
#pragma unroll
            for (int c = 0; c < 4; ++c) {
                Ksf[i * 8 + 2 * c]     = __uint_as_float(rr[c] << 16);
                Ksf[i * 8 + 2 * c + 1] = __uint_as_float(rr[c] & 0xffff0000u);
            }
            r = Vg[i];
            u32 vv[4] = { r.x, r.y, r.z, r.w };
#pragma unroll
            for (int c = 0; c < 4; ++c) {
                Vsf[i * 8 + 2 * c]     = __uint_as_float(vv[c] << 16);
                Vsf[i * 8 + 2 * c + 1] = __uint_as_float(vv[c] & 0xffff0000u);
            }
        }
        __syncthreads();
        for (int t = 0; t < 128; ++t) {
            float p = bf2f(Ps[t * 128 + s]);
#pragma unroll
            for (int j = 0; j < 32; ++j) accK[j] = fmaf(p, Ksf[t * 64 + d0 + j], accK[j]);
#pragma unroll
            for (int j = 0; j < 32; ++j) accV[j] = fmaf(p, Vsf[t * 64 + d0 + j], accV[j]);
        }
        __syncthreads();
    }
    float* base = partial + (size_t)(bh * 4 + chunk) * 16384;
#pragma unroll
    for (int j = 0; j < 32; ++j) {
        base[s * 64 + d0 + j]        = accK[j];
        base[8192 + s * 64 + d0 + j] = accV[j];
    }
}

__global__ __launch_bounds__(256)
void reduce_kernel(const float* __restrict__ partial, float* __restrict__ BKV)
{
    int i = blockIdx.x * 256 + threadIdx.x;
    int bh = i >> 14; int rem = i & 16383;
    float s = 0.f;
#pragma unroll
    for (int c = 0; c < 4; ++c) s += partial[(size_t)(bh * 4 + c) * 16384 + rem];
    BKV[i] = s;
}

// ---------------------------------------------------------------------------
// Attention (unchanged)
// ---------------------------------------------------------------------------
__global__ __launch_bounds__(256)
void attn_kernel(const u16* __restrict__ Qb, const float* __restrict__ BKV,
                 u16* __restrict__ AO)
{
    __shared__ float bKT[64 * 128];
    __shared__ float bVs[128 * 64];
    __shared__ float QsT[64 * 64];
    __shared__ float Ss[64 * 129];
    int tid = threadIdx.x;
    int bh = blockIdx.y, tt0 = blockIdx.x * 64;
    const float* bK = BKV + (size_t)bh * 16384;
    const float* bV = bK + 8192;

    for (int i = tid; i < 8192; i += 256) {
        int s = i >> 6, d = i & 63;
        bKT[d * 128 + s] = bK[i];
        bVs[i] = bV[i];
    }
    for (int i = tid; i < 4096; i += 256) {
        int t = i >> 6, d = i & 63;
        QsT[d * 64 + t] = bf2f(Qb[((size_t)bh * T_ + tt0 + t) * 64 + d]);
    }
    __syncthreads();

    int t0 = (tid >> 4) * 4, c0 = (tid & 15);
    {
        int s0 = c0 * 8;
        float acc[4][8];
#pragma unroll
        for (int i = 0; i < 4; ++i)
#pragma unroll
            for (int j = 0; j < 8; ++j) acc[i][j] = 0.f;
        for (int d = 0; d < 64; ++d) {
            float q[4], b[8];
#pragma unroll
            for (int i = 0; i < 4; ++i) q[i] = QsT[d * 64 + t0 + i];
#pragma unroll
            for (int j = 0; j < 8; ++j) b[j] = bKT[d * 128 + s0 + j];
#pragma unroll
            for (int i = 0; i < 4; ++i)
#pragma unroll
                for (int j = 0; j < 8; ++j) acc[i][j] = fmaf(q[i], b[j], acc[i][j]);
        }
#pragma unroll
        for (int i = 0; i < 4; ++i)
#pragma unroll
            for (int j = 0; j < 8; ++j) Ss[(t0 + i) * 129 + s0 + j] = acc[i][j] * 0.125f;
    }
    __syncthreads();
    if (tid < 64) {
        float mx = -1e30f;
        for (int s2 = 0; s2 < 128; ++s2) mx = fmaxf(mx, Ss[tid * 129 + s2]);
        float sum = 0.f;
        for (int s2 = 0; s2 < 128; ++s2) {
            float e = __expf(Ss[tid * 129 + s2] - mx);
            sum += e; Ss[tid * 129 + s2] = e;
        }
        float isum = 1.f / sum;
        for (int s2 = 0; s2 < 128; ++s2) Ss[tid * 129 + s2] *= isum;
    }
    __syncthreads();
    {
        int d0 = c0 * 4;
        float o[4][4];
#pragma unroll
        for (int i = 0; i < 4; ++i)
#pragma unroll
            for (int j = 0; j < 4; ++j) o[i][j] = 0.f;
        for (int s2 = 0; s2 < 128; ++s2) {
            float pv[4];
#pragma unroll
            for (int i = 0; i < 4; ++i) pv[i] = Ss[(t0 + i) * 129 + s2];
            float4 vv = *(const float4*)&bVs[s2 * 64 + d0];
#pragma unroll
            for (int i = 0; i < 4; ++i) {
                o[i][0] = fmaf(pv[i], vv.x, o[i][0]);
                o[i][1] = fmaf(pv[i], vv.y, o[i][1]);
                o[i][2] = fmaf(pv[i], vv.z, o[i][2]);
                o[i][3] = fmaf(pv[i], vv.w, o[i][3]);
            }
        }
        int bb = bh >> 4, h = bh & 15;
#pragma unroll
        for (int i = 0; i < 4; ++i)
#pragma unroll
            for (int j = 0; j < 4; ++j)
                AO[((size_t)(bb * T_ + tt0 + t0 + i)) * DK_ + h * 64 + d0 + j] = f2bf(o[i][j]);
    }
}

// ---------------------------------------------------------------------------
extern "C" void kernel_launch(void* const* d_in, const int* in_sizes, int n_in,
                              void* d_out, int out_size, void* d_ws, size_t ws_size,
                              hipStream_t stream)
{
    (void)in_sizes; (void)n_in; (void)out_size; (void)ws_size;
    const float* x      = (const float*)d_in[0];
    const float* Wq     = (const float*)d_in[1];
    const float* Wk     = (const float*)d_in[2];
    const float* Wv     = (const float*)d_in[3];
    const float* Wo     = (const float*)d_in[4];
    const float* bo     = (const float*)d_in[5];
    const float* planes = (const float*)d_in[6];
    const float* protos = (const float*)d_in[7];
    const float* ltemp  = (const float*)d_in[8];
    float* out = (float*)d_out;

    char* ws = (char*)d_ws;
    // Region A (splits of x and Wq/Wk/Wv; dead after qkv_mfma) — P aliases it.
    u16* xhi = (u16*)(ws);                         // 33.5 MB
    u16* xlo = (u16*)(ws + 33554432ull);           // 33.5 MB
    u16* hq  = (u16*)(ws + 67108864ull);
    u16* lq  = (u16*)(ws + 69206016ull);
    u16* hk  = (u16*)(ws + 71303168ull);
    u16* lk  = (u16*)(ws + 73400320ull);
    u16* hv  = (u16*)(ws + 75497472ull);
    u16* lv  = (u16*)(ws + 77594624ull);           // region A ends at 79,691,776
    u16* P   = (u16*)(ws);                         // 67.1 MB, aliases region A (hash runs after qkv)
    size_t off = 79691776ull;
    u16* Qb = (u16*)(ws + off); off += 33554432ull;
    u16* Kb = (u16*)(ws + off); off += 33554432ull;
    u16* Vb = (u16*)(ws + off); off += 33554432ull;
    u16* wohi = (u16*)(ws + off); off += 2097152ull;
    u16* wolo = (u16*)(ws + off); off += 2097152ull;
    // AO aliases partial (partial dead before attn writes AO)
    float* partial = (float*)(ws + off);
    u16*   AO      = (u16*)(ws + off); off += 33554432ull;
    float* BKV     = (float*)(ws + off); off += 4194304ull;   // total ~216.5 MB

    split_x<<<dim3(4096), 256, 0, stream>>>(x, xhi, xlo);
    split_w<<<dim3(1024, 1, 4), 256, 0, stream>>>(Wq, Wk, Wv, Wo, hq, lq, hk, lk, hv, lv, wohi, wolo);
    qkv_mfma<<<dim3(128, 8, 3), 256, 0, stream>>>(xhi, xlo, hq, lq, hk, lk, hv, lv, Qb, Kb, Vb);
    hash_kernel<<<dim3(BH_ * T_ / 256), 256, 0, stream>>>(Kb, planes, protos, ltemp, P);
    bucket_kernel<<<dim3(4, 64), 256, 0, stream>>>(P, Kb, Vb, partial);
    reduce_kernel<<<dim3(4096), 256, 0, stream>>>(partial, BKV);
    attn_kernel<<<dim3(64, 64), 256, 0, stream>>>(Qb, BKV, AO);
    out_mfma<<<dim3(128, 8), 256, 0, stream>>>(AO, wohi, wolo, bo, out);
}

// Round 8
// 722.288 us; speedup vs baseline: 3.3129x; 1.6211x over previous
//
#include <hip/hip_runtime.h>
#include <hip/hip_bf16.h>
#include <math.h>

typedef unsigned short u16;
typedef unsigned int   u32;
typedef __attribute__((ext_vector_type(8))) short bf16x8;
typedef __attribute__((ext_vector_type(4))) float f32x4;

#define B_  4
#define T_  4096
#define H_  16
#define DK_ 1024
#define BH_ (B_*H_)      // 64
#define M_  (B_*T_)      // 16384

__device__ __forceinline__ float bf2f(u16 u) { return __uint_as_float(((u32)u) << 16); }
__device__ __forceinline__ u16 f2bf(float f) {
    u32 x = __float_as_uint(f);
    u32 r = (x + 0x7fffu + ((x >> 16) & 1u)) >> 16;   // RNE
    return (u16)r;
}
__device__ __forceinline__ void gld16(const void* g, void* l) {
    __builtin_amdgcn_global_load_lds((__attribute__((address_space(1))) void*)g,
                                     (__attribute__((address_space(3))) void*)l,
                                     16, 0, 0);
}

// ---------------------------------------------------------------------------
__global__ __launch_bounds__(256)
void split_x(const float* __restrict__ x, u16* __restrict__ xhi, u16* __restrict__ xlo)
{
    const size_t n4 = (size_t)M_ * DK_ / 4;
    for (size_t i = (size_t)blockIdx.x * 256 + threadIdx.x; i < n4; i += (size_t)gridDim.x * 256) {
        float4 v = ((const float4*)x)[i];
        float vv[4] = { v.x, v.y, v.z, v.w };
        u32 hw[2], lw[2];
#pragma unroll
        for (int c = 0; c < 2; ++c) {
            u16 h0 = f2bf(vv[2*c]),   h1 = f2bf(vv[2*c+1]);
            u16 l0 = f2bf(vv[2*c]   - bf2f(h0));
            u16 l1 = f2bf(vv[2*c+1] - bf2f(h1));
            hw[c] = (u32)h0 | ((u32)h1 << 16);
            lw[c] = (u32)l0 | ((u32)l1 << 16);
        }
        ((uint2*)xhi)[i] = make_uint2(hw[0], hw[1]);
        ((uint2*)xlo)[i] = make_uint2(lw[0], lw[1]);
    }
}

__global__ __launch_bounds__(256)
void split_w(const float* __restrict__ Wq, const float* __restrict__ Wk,
             const float* __restrict__ Wv, const float* __restrict__ Wo,
             u16* __restrict__ hq, u16* __restrict__ lq,
             u16* __restrict__ hk, u16* __restrict__ lk,
             u16* __restrict__ hv, u16* __restrict__ lv,
             u16* __restrict__ ho, u16* __restrict__ lo_)
{
    int z = blockIdx.z;
    const float* W = (z == 0) ? Wq : (z == 1) ? Wk : (z == 2) ? Wv : Wo;
    u16* ph = (z == 0) ? hq : (z == 1) ? hk : (z == 2) ? hv : ho;
    u16* pl = (z == 0) ? lq : (z == 1) ? lk : (z == 2) ? lv : lo_;
    size_t i = (size_t)blockIdx.x * 256 + threadIdx.x;
    float4 v = ((const float4*)W)[i];
    float vv[4] = { v.x, v.y, v.z, v.w };
    u32 hw[2], lw[2];
#pragma unroll
    for (int c = 0; c < 2; ++c) {
        u16 h0 = f2bf(vv[2*c]),   h1 = f2bf(vv[2*c+1]);
        u16 l0 = f2bf(vv[2*c]   - bf2f(h0));
        u16 l1 = f2bf(vv[2*c+1] - bf2f(h1));
        hw[c] = (u32)h0 | ((u32)h1 << 16);
        lw[c] = (u32)l0 | ((u32)l1 << 16);
    }
    ((uint2*)ph)[i] = make_uint2(hw[0], hw[1]);
    ((uint2*)pl)[i] = make_uint2(lw[0], lw[1]);
}

// ---------------------------------------------------------------------------
// Q GEMM: Qb[bh][t][d] = x @ Wq^T (split-fp32, K=3072). 128x128 tile.
// ---------------------------------------------------------------------------
__global__ __launch_bounds__(256)
void q_mfma(const u16* __restrict__ xhi, const u16* __restrict__ xlo,
            const u16* __restrict__ whi, const u16* __restrict__ wlo,
            u16* __restrict__ Qb)
{
    __shared__ u16 At[128 * 64];
    __shared__ u16 Bt[128 * 64];
    int tid = threadIdx.x, l = tid & 63, w = tid >> 6;
    int row0 = blockIdx.x * 128, col0 = blockIdx.y * 128;
    int wr = (w >> 1) * 64, wc = (w & 1) * 64;
    int srow = l >> 3;
    int scol = ((l & 7) ^ srow) << 3;
    int lane15 = l & 15, lhalf = l >> 4;

    f32x4 acc[4][4];
#pragma unroll
    for (int i = 0; i < 4; ++i)
#pragma unroll
        for (int j = 0; j < 4; ++j) acc[i][j] = (f32x4){0.f, 0.f, 0.f, 0.f};

    int aoff[4][2], boff[4][2];
#pragma unroll
    for (int f = 0; f < 4; ++f)
#pragma unroll
        for (int ks = 0; ks < 2; ++ks) {
            int sw = (lane15 & 7) << 3;
            aoff[f][ks] = (wr + f * 16 + lane15) * 64 + ((lhalf * 8 + ks * 32) ^ sw);
            boff[f][ks] = (wc + f * 16 + lane15) * 64 + ((lhalf * 8 + ks * 32) ^ sw);
        }

    for (int kb = 0; kb < 3072; kb += 64) {
        int seg = kb >> 10, kc = kb & 1023;
        const u16* Asrc = (seg == 1) ? xlo : xhi;
        const u16* Bsrc = (seg == 2) ? wlo : whi;
#pragma unroll
        for (int i2 = 0; i2 < 4; ++i2) {
            int c = w * 4 + i2;
            gld16(Asrc + (size_t)(row0 + c * 8 + srow) * 1024 + kc + scol, (char*)At + c * 1024);
            gld16(Bsrc + (size_t)(col0 + c * 8 + srow) * 1024 + kc + scol, (char*)Bt + c * 1024);
        }
        __syncthreads();
#pragma unroll
        for (int ks = 0; ks < 2; ++ks) {
            bf16x8 a[4], b[4];
#pragma unroll
            for (int f = 0; f < 4; ++f) a[f] = *(const bf16x8*)&At[aoff[f][ks]];
#pragma unroll
            for (int f = 0; f < 4; ++f) b[f] = *(const bf16x8*)&Bt[boff[f][ks]];
#pragma unroll
            for (int fi = 0; fi < 4; ++fi)
#pragma unroll
                for (int fj = 0; fj < 4; ++fj)
                    acc[fi][fj] = __builtin_amdgcn_mfma_f32_16x16x32_bf16(a[fi], b[fj], acc[fi][fj], 0, 0, 0);
        }
        __syncthreads();
    }
#pragma unroll
    for (int fi = 0; fi < 4; ++fi)
#pragma unroll
        for (int j = 0; j < 4; ++j) {
            int m = row0 + wr + fi * 16 + lhalf * 4 + j;
            int b_ = m >> 12, t = m & 4095;
#pragma unroll
            for (int fj = 0; fj < 4; ++fj) {
                int n = col0 + wc + fj * 16 + lane15;
                int h = n >> 6, d = n & 63;
                Qb[((size_t)(b_ * H_ + h) * T_ + t) * 64 + d] = f2bf(acc[fi][fj][j]);
            }
        }
}

// ---------------------------------------------------------------------------
// K/V GEMM swapped: C[m=(h,d)][n=token] = W @ x^T  -> KT/VT[bh][d][t].
// A'' = [whi|whi|wlo], B'' = [xhi|xlo|xhi]. Grid (8, 128, 2).
// ---------------------------------------------------------------------------
__global__ __launch_bounds__(256)
void kv_mfma(const u16* __restrict__ xhi, const u16* __restrict__ xlo,
             const u16* __restrict__ hk, const u16* __restrict__ lk,
             const u16* __restrict__ hv, const u16* __restrict__ lv,
             u16* __restrict__ KT, u16* __restrict__ VT)
{
    __shared__ u16 At[128 * 64];
    __shared__ u16 Bt[128 * 64];
    int z = blockIdx.z;
    const u16* whi = z ? hv : hk;
    const u16* wlo = z ? lv : lk;
    u16* C = z ? VT : KT;

    int tid = threadIdx.x, l = tid & 63, w = tid >> 6;
    int row0 = blockIdx.x * 128, col0 = blockIdx.y * 128;
    int wr = (w >> 1) * 64, wc = (w & 1) * 64;
    int srow = l >> 3;
    int scol = ((l & 7) ^ srow) << 3;
    int lane15 = l & 15, lhalf = l >> 4;

    f32x4 acc[4][4];
#pragma unroll
    for (int i = 0; i < 4; ++i)
#pragma unroll
        for (int j = 0; j < 4; ++j) acc[i][j] = (f32x4){0.f, 0.f, 0.f, 0.f};

    int aoff[4][2], boff[4][2];
#pragma unroll
    for (int f = 0; f < 4; ++f)
#pragma unroll
        for (int ks = 0; ks < 2; ++ks) {
            int sw = (lane15 & 7) << 3;
            aoff[f][ks] = (wr + f * 16 + lane15) * 64 + ((lhalf * 8 + ks * 32) ^ sw);
            boff[f][ks] = (wc + f * 16 + lane15) * 64 + ((lhalf * 8 + ks * 32) ^ sw);
        }

    for (int kb = 0; kb < 3072; kb += 64) {
        int seg = kb >> 10, kc = kb & 1023;
        const u16* Asrc = (seg == 2) ? wlo : whi;
        const u16* Bsrc = (seg == 1) ? xlo : xhi;
#pragma unroll
        for (int i2 = 0; i2 < 4; ++i2) {
            int c = w * 4 + i2;
            gld16(Asrc + (size_t)(row0 + c * 8 + srow) * 1024 + kc + scol, (char*)At + c * 1024);
            gld16(Bsrc + (size_t)(col0 + c * 8 + srow) * 1024 + kc + scol, (char*)Bt + c * 1024);
        }
        __syncthreads();
#pragma unroll
        for (int ks = 0; ks < 2; ++ks) {
            bf16x8 a[4], b[4];
#pragma unroll
            for (int f = 0; f < 4; ++f) a[f] = *(const bf16x8*)&At[aoff[f][ks]];
#pragma unroll
            for (int f = 0; f < 4; ++f) b[f] = *(const bf16x8*)&Bt[boff[f][ks]];
#pragma unroll
            for (int fi = 0; fi < 4; ++fi)
#pragma unroll
                for (int fj = 0; fj < 4; ++fj)
                    acc[fi][fj] = __builtin_amdgcn_mfma_f32_16x16x32_bf16(a[fi], b[fj], acc[fi][fj], 0, 0, 0);
        }
        __syncthreads();
    }
    // C[m=(h,d)][n=token] -> [bh][d][t]
#pragma unroll
    for (int fi = 0; fi < 4; ++fi)
#pragma unroll
        for (int j = 0; j < 4; ++j) {
            int m = row0 + wr + fi * 16 + lhalf * 4 + j;     // 0..1023
            int h = m >> 6, d = m & 63;
#pragma unroll
            for (int fj = 0; fj < 4; ++fj) {
                int tt = col0 + wc + fj * 16 + lane15;       // 0..16383
                int b_ = tt >> 12, t = tt & 4095;
                C[((size_t)((b_ * H_ + h) * 64 + d)) * T_ + t] = f2bf(acc[fi][fj][j]);
            }
        }
}

// ---------------------------------------------------------------------------
// Soft-hash: reads KT[bh][d][t] (coalesced), writes PT[bh][s][t] (coalesced).
// Grid: 64 bh x 16 tgroups; thread = one token.
// ---------------------------------------------------------------------------
__global__ __launch_bounds__(256)
void hash_kernel(const u16* __restrict__ KT, const float* __restrict__ planes,
                 const float* __restrict__ protos, const float* __restrict__ ltemp,
                 u16* __restrict__ PT)
{
    __shared__ float pl[2048];
    __shared__ float pr[64];
    int tid = threadIdx.x;
    for (int i = tid; i < 2048; i += 256) pl[i] = planes[i];
    if (tid < 64) pr[tid] = protos[tid];
    __syncthreads();

    float sc = __expf(ltemp[0]);
    sc = fminf(fmaxf(sc, 0.01f), 20.0f);
    float inv = 1.0f / sc;

    int bh = blockIdx.x >> 4, tg = blockIdx.x & 15;
    int t = tg * 256 + tid;
    const u16* kbase = KT + (size_t)bh * 64 * T_ + t;

    float proj[32];
#pragma unroll
    for (int p = 0; p < 32; ++p) proj[p] = 0.f;
    for (int d = 0; d < 64; ++d) {
        float kd = bf2f(kbase[(size_t)d * T_]);
#pragma unroll
        for (int p = 0; p < 32; ++p) proj[p] += kd * pl[d * 32 + p];
    }
#pragma unroll
    for (int p = 0; p < 32; ++p) {
        float e = __expf(2.f * proj[p]);
        proj[p] = (1.f - 2.f / (e + 1.f)) * inv;
    }

    u16* obase = PT + (size_t)bh * 128 * T_ + t;
    for (int lt = 0; lt < 8; ++lt) {
        float lg[16];
        float mx = -1e30f;
#pragma unroll
        for (int r = 0; r < 16; ++r) {
            float s = 0.f;
#pragma unroll
            for (int kbit = 0; kbit < 4; ++kbit) s += proj[lt * 4 + kbit] * pr[kbit * 16 + r];
            lg[r] = s; mx = fmaxf(mx, s);
        }
        float sum = 0.f;
#pragma unroll
        for (int r = 0; r < 16; ++r) { lg[r] = __expf(lg[r] - mx); sum += lg[r]; }
        float is = 1.f / sum;
#pragma unroll
        for (int r = 0; r < 16; ++r)
            obase[(size_t)(lt * 16 + r) * T_] = f2bf(lg[r] * is);
    }
}

// ---------------------------------------------------------------------------
// Bucket MFMA: per (chunk of 512 tokens, bh):
//   BK[s][d]  += PT[s][t] * KT[d][t]   (waves 0,1: s-halves)
//   BVT[d][s] += VT[d][t] * PT[s][t]   (waves 2,3: s-col-halves)
// partial[bh][chunk][2][8192] fp32. Grid (8, 64).
// ---------------------------------------------------------------------------
__global__ __launch_bounds__(256)
void bucket_mfma(const u16* __restrict__ PT, const u16* __restrict__ KT,
                 const u16* __restrict__ VT, float* __restrict__ partial)
{
    __shared__ u16 PTs[128 * 64];
    __shared__ u16 KTs[64 * 64];
    __shared__ u16 VTs[64 * 64];
    int tid = threadIdx.x, l = tid & 63, w = tid >> 6;
    int chunk = blockIdx.x, bh = blockIdx.y;
    int srow = l >> 3;
    int scol = ((l & 7) ^ srow) << 3;
    int lane15 = l & 15, lhalf = l >> 4;

    f32x4 acc[4][4];
#pragma unroll
    for (int i = 0; i < 4; ++i)
#pragma unroll
        for (int j = 0; j < 4; ++j) acc[i][j] = (f32x4){0.f, 0.f, 0.f, 0.f};

    // LDS operand bases per wave role
    const u16* Al = (w < 2) ? PTs : VTs;
    const u16* Bl = (w < 2) ? KTs : PTs;
    int arow0 = (w < 2) ? w * 64 : 0;
    int brow0 = (w < 2) ? 0 : (w - 2) * 64;

    int aoff[4][2], boff[4][2];
#pragma unroll
    for (int f = 0; f < 4; ++f)
#pragma unroll
        for (int ks = 0; ks < 2; ++ks) {
            int sw = (lane15 & 7) << 3;
            aoff[f][ks] = (arow0 + f * 16 + lane15) * 64 + ((lhalf * 8 + ks * 32) ^ sw);
            boff[f][ks] = (brow0 + f * 16 + lane15) * 64 + ((lhalf * 8 + ks * 32) ^ sw);
        }

    const u16* PTg = PT + (size_t)bh * 128 * T_;
    const u16* KTg = KT + (size_t)bh * 64 * T_;
    const u16* VTg = VT + (size_t)bh * 64 * T_;

    for (int step = 0; step < 8; ++step) {
        int t0 = chunk * 512 + step * 64;
#pragma unroll
        for (int i2 = 0; i2 < 8; ++i2) {
            int c = w * 8 + i2;          // 0..31
            if (c < 16) {
                gld16(PTg + (size_t)(c * 8 + srow) * T_ + t0 + scol, (char*)PTs + c * 1024);
            } else if (c < 24) {
                int cc = c - 16;
                gld16(KTg + (size_t)(cc * 8 + srow) * T_ + t0 + scol, (char*)KTs + cc * 1024);
            } else {
                int cc = c - 24;
                gld16(VTg + (size_t)(cc * 8 + srow) * T_ + t0 + scol, (char*)VTs + cc * 1024);
            }
        }
        __syncthreads();
#pragma unroll
        for (int ks = 0; ks < 2; ++ks) {
            bf16x8 a[4], b[4];
#pragma unroll
            for (int f = 0; f < 4; ++f) a[f] = *(const bf16x8*)&Al[aoff[f][ks]];
#pragma unroll
            for (int f = 0; f < 4; ++f) b[f] = *(const bf16x8*)&Bl[boff[f][ks]];
#pragma unroll
            for (int fi = 0; fi < 4; ++fi)
#pragma unroll
                for (int fj = 0; fj < 4; ++fj)
                    acc[fi][fj] = __builtin_amdgcn_mfma_f32_16x16x32_bf16(a[fi], b[fj], acc[fi][fj], 0, 0, 0);
        }
        __syncthreads();
    }

    float* base = partial + (size_t)(bh * 8 + chunk) * 16384;
#pragma unroll
    for (int fi = 0; fi < 4; ++fi)
#pragma unroll
        for (int j = 0; j < 4; ++j) {
            int m = fi * 16 + lhalf * 4 + j;
#pragma unroll
            for (int fj = 0; fj < 4; ++fj) {
                int n = fj * 16 + lane15;
                if (w < 2)  base[(w * 64 + m) * 64 + n] = acc[fi][fj][j];
                else        base[8192 + m * 128 + (w - 2) * 64 + n] = acc[fi][fj][j];
            }
        }
}

// Reduce 8 chunk-partials -> hi/lo bf16: BKhi/lo[bh][128][64], BVThi/lo[bh][64][128]
__global__ __launch_bounds__(256)
void reduce_kernel(const float* __restrict__ partial,
                   u16* __restrict__ BKhi, u16* __restrict__ BKlo,
                   u16* __restrict__ BVThi, u16* __restrict__ BVTlo)
{
    int i = blockIdx.x * 256 + threadIdx.x;      // < 64*16384
    int bh = i >> 14, rem = i & 16383;
    float s = 0.f;
#pragma unroll
    for (int c = 0; c < 8; ++c) s += partial[(size_t)(bh * 8 + c) * 16384 + rem];
    u16 h = f2bf(s);
    u16 lo = f2bf(s - bf2f(h));
    if (rem < 8192) { BKhi[bh * 8192 + rem] = h;  BKlo[bh * 8192 + rem] = lo; }
    else            { BVThi[bh * 8192 + rem - 8192] = h; BVTlo[bh * 8192 + rem - 8192] = lo; }
}

// ---------------------------------------------------------------------------
// Attention scores + softmax: per (qtile 128, bh):
//   S = Q @ BK^T / 8 (hi+lo), wave-parallel softmax -> Pattn[bh][t][s] bf16.
// Grid (32, 64). Wave w owns q in [w*32, w*32+32).
// ---------------------------------------------------------------------------
__global__ __launch_bounds__(256)
void attn_scores(const u16* __restrict__ Qb, const u16* __restrict__ BKhi,
                 const u16* __restrict__ BKlo, u16* __restrict__ Pattn)
{
    __shared__ u16 Qs[128 * 64];
    __shared__ u16 Kh[128 * 64];
    __shared__ u16 Kl[128 * 64];
    int tid = threadIdx.x, l = tid & 63, w = tid >> 6;
    int qt = blockIdx.x, bh = blockIdx.y;
    int srow = l >> 3;
    int scol = ((l & 7) ^ srow) << 3;
    int lane15 = l & 15, lhalf = l >> 4;

    const u16* Qg = Qb + ((size_t)bh * T_ + qt * 128) * 64;
    const u16* Khg = BKhi + (size_t)bh * 8192;
    const u16* Klg = BKlo + (size_t)bh * 8192;

#pragma unroll
    for (int i2 = 0; i2 < 12; ++i2) {
        int c = w * 12 + i2;            // 0..47
        if (c < 16)      gld16(Qg  + (size_t)(c * 8 + srow) * 64 + scol,        (char*)Qs + c * 1024);
        else if (c < 32) gld16(Khg + (size_t)((c-16) * 8 + srow) * 64 + scol,   (char*)Kh + (c-16) * 1024);
        else             gld16(Klg + (size_t)((c-32) * 8 + srow) * 64 + scol,   (char*)Kl + (c-32) * 1024);
    }
    __syncthreads();

    f32x4 acc[2][8];
#pragma unroll
    for (int i = 0; i < 2; ++i)
#pragma unroll
        for (int j = 0; j < 8; ++j) acc[i][j] = (f32x4){0.f, 0.f, 0.f, 0.f};

    int sw = (lane15 & 7) << 3;
    bf16x8 a[2][2];
#pragma unroll
    for (int fi = 0; fi < 2; ++fi)
#pragma unroll
        for (int ks = 0; ks < 2; ++ks)
            a[fi][ks] = *(const bf16x8*)&Qs[(w * 32 + fi * 16 + lane15) * 64 + ((lhalf * 8 + ks * 32) ^ sw)];

#pragma unroll
    for (int kp = 0; kp < 2; ++kp) {
        const u16* Bl = kp ? Kl : Kh;
#pragma unroll
        for (int ks = 0; ks < 2; ++ks)
#pragma unroll
            for (int fj = 0; fj < 8; ++fj) {
                bf16x8 b = *(const bf16x8*)&Bl[(fj * 16 + lane15) * 64 + ((lhalf * 8 + ks * 32) ^ sw)];
#pragma unroll
                for (int fi = 0; fi < 2; ++fi)
                    acc[fi][fj] = __builtin_amdgcn_mfma_f32_16x16x32_bf16(a[fi][ks], b, acc[fi][fj], 0, 0, 0);
            }
    }

    // wave-parallel softmax per q-row (8 regs + shfl over lane15 bits)
    u16* Pg = Pattn + ((size_t)bh * T_ + qt * 128) * 128;
#pragma unroll
    for (int fi = 0; fi < 2; ++fi)
#pragma unroll
        for (int j = 0; j < 4; ++j) {
            float v[8];
            float mx = -1e30f;
#pragma unroll
            for (int fj = 0; fj < 8; ++fj) { v[fj] = acc[fi][fj][j] * 0.125f; mx = fmaxf(mx, v[fj]); }
            mx = fmaxf(mx, __shfl_xor(mx, 1));
            mx = fmaxf(mx, __shfl_xor(mx, 2));
            mx = fmaxf(mx, __shfl_xor(mx, 4));
            mx = fmaxf(mx, __shfl_xor(mx, 8));
            float sum = 0.f;
#pragma unroll
            for (int fj = 0; fj < 8; ++fj) { v[fj] = __expf(v[fj] - mx); sum += v[fj]; }
            sum += __shfl_xor(sum, 1);
            sum += __shfl_xor(sum, 2);
            sum += __shfl_xor(sum, 4);
            sum += __shfl_xor(sum, 8);
            float is = 1.f / sum;
            int q = w * 32 + fi * 16 + lhalf * 4 + j;
#pragma unroll
            for (int fj = 0; fj < 8; ++fj)
                Pg[(size_t)q * 128 + fj * 16 + lane15] = f2bf(v[fj] * is);
        }
}

// ---------------------------------------------------------------------------
// PV: O = P @ BVT^T (hi+lo) -> AO[(b,t)][(h,d)] bf16. Grid (32, 64).
// LDS: Ps[128][128] + BVh[64][128] + BVl[64][128] = 64 KiB.
// ---------------------------------------------------------------------------
__global__ __launch_bounds__(256)
void attn_pv(const u16* __restrict__ Pattn, const u16* __restrict__ BVThi,
             const u16* __restrict__ BVTlo, u16* __restrict__ AO)
{
    __shared__ u16 Ps[128 * 128];
    __shared__ u16 BVh[64 * 128];
    __shared__ u16 BVl[64 * 128];
    int tid = threadIdx.x, l = tid & 63, w = tid >> 6;
    int qt = blockIdx.x, bh = blockIdx.y;
    int lane15 = l & 15, lhalf = l >> 4;

    const u16* Pg = Pattn + ((size_t)bh * T_ + qt * 128) * 128;
    const u16* Vh = BVThi + (size_t)bh * 8192;
    const u16* Vl = BVTlo + (size_t)bh * 8192;

    // 128-elem rows: chunk = 4 rows; lane row = l>>4, granule = l&15.
#pragma unroll
    for (int i2 = 0; i2 < 16; ++i2) {
        int c = w * 16 + i2;            // 0..63
        int rl = l >> 4;
        if (c < 32) {
            int row = c * 4 + rl;
            int g = ((l & 15) ^ (row & 7)) << 3;
            gld16(Pg + (size_t)row * 128 + g, (char*)Ps + c * 1024);
        } else if (c < 48) {
            int cc = c - 32;
            int row = cc * 4 + rl;
            int g = ((l & 15) ^ (row & 7)) << 3;
            gld16(Vh + (size_t)row * 128 + g, (char*)BVh + cc * 1024);
        } else {
            int cc = c - 48;
            int row = cc * 4 + rl;
            int g = ((l & 15) ^ (row & 7)) << 3;
            gld16(Vl + (size_t)row * 128 + g, (char*)BVl + cc * 1024);
        }
    }
    __syncthreads();

    f32x4 acc[2][4];
#pragma unroll
    for (int i = 0; i < 2; ++i)
#pragma unroll
        for (int j = 0; j < 4; ++j) acc[i][j] = (f32x4){0.f, 0.f, 0.f, 0.f};

    int sw = (lane15 & 7) << 3;
    bf16x8 a[4][2];
#pragma unroll
    for (int ks = 0; ks < 4; ++ks)
#pragma unroll
        for (int fi = 0; fi < 2; ++fi)
            a[ks][fi] = *(const bf16x8*)&Ps[(w * 32 + fi * 16 + lane15) * 128 + ((lhalf * 8 + ks * 32) ^ sw)];

#pragma unroll
    for (int kk = 0; kk < 8; ++kk) {
        int ks = kk & 3;
        const u16* Bl = (kk < 4) ? BVh : BVl;
#pragma unroll
        for (int fj = 0; fj < 4; ++fj) {
            bf16x8 b = *(const bf16x8*)&Bl[(fj * 16 + lane15) * 128 + ((lhalf * 8 + ks * 32) ^ sw)];
#pragma unroll
            for (int fi = 0; fi < 2; ++fi)
                acc[fi][fj] = __builtin_amdgcn_mfma_f32_16x16x32_bf16(a[ks][fi], b, acc[fi][fj], 0, 0, 0);
        }
    }

    int b_ = bh >> 4, h = bh & 15;
#pragma unroll
    for (int fi = 0; fi < 2; ++fi)
#pragma unroll
        for (int j = 0; j < 4; ++j) {
            int t = qt * 128 + w * 32 + fi * 16 + lhalf * 4 + j;
#pragma unroll
            for (int fj = 0; fj < 4; ++fj) {
                int d = fj * 16 + lane15;
                AO[((size_t)(b_ * T_ + t)) * DK_ + h * 64 + d] = f2bf(acc[fi][fj][j]);
            }
        }
}

// ---------------------------------------------------------------------------
// Output GEMM (unchanged): out = AO @ [Wohi|Wolo]^T + bo, fp32 out.
// ---------------------------------------------------------------------------
__global__ __launch_bounds__(256)
void out_mfma(const u16* __restrict__ AO, const u16* __restrict__ wohi,
              const u16* __restrict__ wolo, const float* __restrict__ bo,
              float* __restrict__ out)
{
    __shared__ u16 At[128 * 64];
    __shared__ u16 Bt[128 * 64];
    int tid = threadIdx.x, l = tid & 63, w = tid >> 6;
    int row0 = blockIdx.x * 128, col0 = blockIdx.y * 128;
    int wr = (w >> 1) * 64, wc = (w & 1) * 64;
    int srow = l >> 3;
    int scol = ((l & 7) ^ srow) << 3;
    int lane15 = l & 15, lhalf = l >> 4;

    f32x4 acc[4][4];
#pragma unroll
    for (int i = 0; i < 4; ++i)
#pragma unroll
        for (int j = 0; j < 4; ++j) acc[i][j] = (f32x4){0.f, 0.f, 0.f, 0.f};

    int aoff[4][2], boff[4][2];
#pragma unroll
    for (int f = 0; f < 4; ++f)
#pragma unroll
        for (int ks = 0; ks < 2; ++ks) {
            int sw = (lane15 & 7) << 3;
            aoff[f][ks] = (wr + f * 16 + lane15) * 64 + ((lhalf * 8 + ks * 32) ^ sw);
            boff[f][ks] = (wc + f * 16 + lane15) * 64 + ((lhalf * 8 + ks * 32) ^ sw);
        }

    for (int kb = 0; kb < 2048; kb += 64) {
        int seg = kb >> 10, kc = kb & 1023;
        const u16* Bsrc = seg ? wolo : wohi;
#pragma unroll
        for (int i2 = 0; i2 < 4; ++i2) {
            int c = w * 4 + i2;
            gld16(AO + (size_t)(row0 + c * 8 + srow) * 1024 + kc + scol, (char*)At + c * 1024);
            gld16(Bsrc + (size_t)(col0 + c * 8 + srow) * 1024 + kc + scol, (char*)Bt + c * 1024);
        }
        __syncthreads();
#pragma unroll
        for (int ks = 0; ks < 2; ++ks) {
            bf16x8 a[4], b[4];
#pragma unroll
            for (int f = 0; f < 4; ++f) a[f] = *(const bf16x8*)&At[aoff[f][ks]];
#pragma unroll
            for (int f = 0; f < 4; ++f) b[f] = *(const bf16x8*)&Bt[boff[f][ks]];
#pragma unroll
            for (int fi = 0; fi < 4; ++fi)
#pragma unroll
                for (int fj = 0; fj < 4; ++fj)
                    acc[fi][fj] = __builtin_amdgcn_mfma_f32_16x16x32_bf16(a[fi], b[fj], acc[fi][fj], 0, 0, 0);
        }
        __syncthreads();
    }
#pragma unroll
    for (int fi = 0; fi < 4; ++fi)
#pragma unroll
        for (int j = 0; j < 4; ++j) {
            size_t m = row0 + wr + fi * 16 + lhalf * 4 + j;
#pragma unroll
            for (int fj = 0; fj < 4; ++fj) {
                int n = col0 + wc + fj * 16 + lane15;
                out[m * DK_ + n] = acc[fi][fj][j] + bo[n];
            }
        }
}

// ---------------------------------------------------------------------------
extern "C" void kernel_launch(void* const* d_in, const int* in_sizes, int n_in,
                              void* d_out, int out_size, void* d_ws, size_t ws_size,
                              hipStream_t stream)
{
    (void)in_sizes; (void)n_in; (void)out_size; (void)ws_size;
    const float* x      = (const float*)d_in[0];
    const float* Wq     = (const float*)d_in[1];
    const float* Wk     = (const float*)d_in[2];
    const float* Wv     = (const float*)d_in[3];
    const float* Wo     = (const float*)d_in[4];
    const float* bo     = (const float*)d_in[5];
    const float* planes = (const float*)d_in[6];
    const float* protos = (const float*)d_in[7];
    const float* ltemp  = (const float*)d_in[8];
    float* out = (float*)d_out;

    char* ws = (char*)d_ws;
    u16* xhi = (u16*)(ws + 0ull);             // 33.5MB; later PT (67MB) then Pattn
    u16* xlo = (u16*)(ws + 33554432ull);
    u16* Qb  = (u16*)(ws + 67108864ull);      // 33.5MB
    u16* KT  = (u16*)(ws + 100663296ull);     // 33.5MB
    u16* VT  = (u16*)(ws + 134217728ull);     // 33.5MB
    u16* hq  = (u16*)(ws + 167772160ull);     // weight splits 12MB (dead after q/kv)
    u16* lq  = (u16*)(ws + 169869312ull);
    u16* hk  = (u16*)(ws + 171966464ull);
    u16* lk  = (u16*)(ws + 174063616ull);
    u16* hv  = (u16*)(ws + 176160768ull);
    u16* lv  = (u16*)(ws + 178257920ull);
    u16* BKhi  = (u16*)(ws + 167772160ull);   // alias w-splits (after reduce)
    u16* BKlo  = (u16*)(ws + 168820736ull);
    u16* BVThi = (u16*)(ws + 169869312ull);
    u16* BVTlo = (u16*)(ws + 170917888ull);
    u16* wohi = (u16*)(ws + 180355072ull);    // 2MB each, live till end
    u16* wolo = (u16*)(ws + 182452224ull);
    float* partial = (float*)(ws + 184549376ull);  // 33.5MB; later AO
    u16*   AO      = (u16*)(ws + 184549376ull);
    u16* PT    = (u16*)(ws + 0ull);           // 67MB, aliases xhi+xlo
    u16* Pattn = (u16*)(ws + 0ull);           // 67MB, aliases PT (after bucket)

    split_x<<<dim3(4096), 256, 0, stream>>>(x, xhi, xlo);
    split_w<<<dim3(1024, 1, 4), 256, 0, stream>>>(Wq, Wk, Wv, Wo, hq, lq, hk, lk, hv, lv, wohi, wolo);
    q_mfma<<<dim3(128, 8), 256, 0, stream>>>(xhi, xlo, hq, lq, Qb);
    kv_mfma<<<dim3(8, 128, 2), 256, 0, stream>>>(xhi, xlo, hk, lk, hv, lv, KT, VT);
    hash_kernel<<<dim3(1024), 256, 0, stream>>>(KT, planes, protos, ltemp, PT);
    bucket_mfma<<<dim3(8, 64), 256, 0, stream>>>(PT, KT, VT, partial);
    reduce_kernel<<<dim3(4096), 256, 0, stream>>>(partial, BKhi, BKlo, BVThi, BVTlo);
    attn_scores<<<dim3(32, 64), 256, 0, stream>>>(Qb, BKhi, BKlo, Pattn);
    attn_pv<<<dim3(32, 64), 256, 0, stream>>>(Pattn, BVThi, BVTlo, AO);
    out_mfma<<<dim3(128, 8), 256, 0, stream>>>(AO, wohi, wolo, bo, out);
}

// Round 9
// 706.343 us; speedup vs baseline: 3.3876x; 1.0226x over previous
//
#include <hip/hip_runtime.h>
#include <hip/hip_bf16.h>
#include <math.h>

typedef unsigned short u16;
typedef unsigned int   u32;
typedef __attribute__((ext_vector_type(8))) short bf16x8;
typedef __attribute__((ext_vector_type(4))) float f32x4;

#define B_  4
#define T_  4096
#define H_  16
#define DK_ 1024
#define BH_ (B_*H_)      // 64
#define M_  (B_*T_)      // 16384

__device__ __forceinline__ float bf2f(u16 u) { return __uint_as_float(((u32)u) << 16); }
__device__ __forceinline__ u16 f2bf(float f) {
    u32 x = __float_as_uint(f);
    u32 r = (x + 0x7fffu + ((x >> 16) & 1u)) >> 16;   // RNE
    return (u16)r;
}
__device__ __forceinline__ void gld16(const void* g, void* l) {
    __builtin_amdgcn_global_load_lds((__attribute__((address_space(1))) void*)g,
                                     (__attribute__((address_space(3))) void*)l,
                                     16, 0, 0);
}

// ---------------------------------------------------------------------------
__global__ __launch_bounds__(256)
void split_x(const float* __restrict__ x, u16* __restrict__ xhi, u16* __restrict__ xlo)
{
    const size_t n4 = (size_t)M_ * DK_ / 4;
    for (size_t i = (size_t)blockIdx.x * 256 + threadIdx.x; i < n4; i += (size_t)gridDim.x * 256) {
        float4 v = ((const float4*)x)[i];
        float vv[4] = { v.x, v.y, v.z, v.w };
        u32 hw[2], lw[2];
#pragma unroll
        for (int c = 0; c < 2; ++c) {
            u16 h0 = f2bf(vv[2*c]),   h1 = f2bf(vv[2*c+1]);
            u16 l0 = f2bf(vv[2*c]   - bf2f(h0));
            u16 l1 = f2bf(vv[2*c+1] - bf2f(h1));
            hw[c] = (u32)h0 | ((u32)h1 << 16);
            lw[c] = (u32)l0 | ((u32)l1 << 16);
        }
        ((uint2*)xhi)[i] = make_uint2(hw[0], hw[1]);
        ((uint2*)xlo)[i] = make_uint2(lw[0], lw[1]);
    }
}

__global__ __launch_bounds__(256)
void split_w(const float* __restrict__ Wq, const float* __restrict__ Wk,
             const float* __restrict__ Wv, const float* __restrict__ Wo,
             u16* __restrict__ hq, u16* __restrict__ lq,
             u16* __restrict__ hk, u16* __restrict__ lk,
             u16* __restrict__ hv, u16* __restrict__ lv,
             u16* __restrict__ ho, u16* __restrict__ lo_)
{
    int z = blockIdx.z;
    const float* W = (z == 0) ? Wq : (z == 1) ? Wk : (z == 2) ? Wv : Wo;
    u16* ph = (z == 0) ? hq : (z == 1) ? hk : (z == 2) ? hv : ho;
    u16* pl = (z == 0) ? lq : (z == 1) ? lk : (z == 2) ? lv : lo_;
    size_t i = (size_t)blockIdx.x * 256 + threadIdx.x;
    float4 v = ((const float4*)W)[i];
    float vv[4] = { v.x, v.y, v.z, v.w };
    u32 hw[2], lw[2];
#pragma unroll
    for (int c = 0; c < 2; ++c) {
        u16 h0 = f2bf(vv[2*c]),   h1 = f2bf(vv[2*c+1]);
        u16 l0 = f2bf(vv[2*c]   - bf2f(h0));
        u16 l1 = f2bf(vv[2*c+1] - bf2f(h1));
        hw[c] = (u32)h0 | ((u32)h1 << 16);
        lw[c] = (u32)l0 | ((u32)l1 << 16);
    }
    ((uint2*)ph)[i] = make_uint2(hw[0], hw[1]);
    ((uint2*)pl)[i] = make_uint2(lw[0], lw[1]);
}

// ---------------------------------------------------------------------------
// Q GEMM: Qb[bh][t][d] = x @ Wq^T (split-fp32, K=3072). 128x128 tile.
// ---------------------------------------------------------------------------
__global__ __launch_bounds__(256)
void q_mfma(const u16* __restrict__ xhi, const u16* __restrict__ xlo,
            const u16* __restrict__ whi, const u16* __restrict__ wlo,
            u16* __restrict__ Qb)
{
    __shared__ u16 At[128 * 64];
    __shared__ u16 Bt[128 * 64];
    int tid = threadIdx.x, l = tid & 63, w = tid >> 6;
    int row0 = blockIdx.x * 128, col0 = blockIdx.y * 128;
    int wr = (w >> 1) * 64, wc = (w & 1) * 64;
    int srow = l >> 3;
    int scol = ((l & 7) ^ srow) << 3;
    int lane15 = l & 15, lhalf = l >> 4;

    f32x4 acc[4][4];
#pragma unroll
    for (int i = 0; i < 4; ++i)
#pragma unroll
        for (int j = 0; j < 4; ++j) acc[i][j] = (f32x4){0.f, 0.f, 0.f, 0.f};

    int aoff[4][2], boff[4][2];
#pragma unroll
    for (int f = 0; f < 4; ++f)
#pragma unroll
        for (int ks = 0; ks < 2; ++ks) {
            int sw = (lane15 & 7) << 3;
            aoff[f][ks] = (wr + f * 16 + lane15) * 64 + ((lhalf * 8 + ks * 32) ^ sw);
            boff[f][ks] = (wc + f * 16 + lane15) * 64 + ((lhalf * 8 + ks * 32) ^ sw);
        }

    for (int kb = 0; kb < 3072; kb += 64) {
        int seg = kb >> 10, kc = kb & 1023;
        const u16* Asrc = (seg == 1) ? xlo : xhi;
        const u16* Bsrc = (seg == 2) ? wlo : whi;
#pragma unroll
        for (int i2 = 0; i2 < 4; ++i2) {
            int c = w * 4 + i2;
            gld16(Asrc + (size_t)(row0 + c * 8 + srow) * 1024 + kc + scol, (char*)At + c * 1024);
            gld16(Bsrc + (size_t)(col0 + c * 8 + srow) * 1024 + kc + scol, (char*)Bt + c * 1024);
        }
        __syncthreads();
#pragma unroll
        for (int ks = 0; ks < 2; ++ks) {
            bf16x8 a[4], b[4];
#pragma unroll
            for (int f = 0; f < 4; ++f) a[f] = *(const bf16x8*)&At[aoff[f][ks]];
#pragma unroll
            for (int f = 0; f < 4; ++f) b[f] = *(const bf16x8*)&Bt[boff[f][ks]];
#pragma unroll
            for (int fi = 0; fi < 4; ++fi)
#pragma unroll
                for (int fj = 0; fj < 4; ++fj)
                    acc[fi][fj] = __builtin_amdgcn_mfma_f32_16x16x32_bf16(a[fi], b[fj], acc[fi][fj], 0, 0, 0);
        }
        __syncthreads();
    }
#pragma unroll
    for (int fi = 0; fi < 4; ++fi)
#pragma unroll
        for (int j = 0; j < 4; ++j) {
            int m = row0 + wr + fi * 16 + lhalf * 4 + j;
            int b_ = m >> 12, t = m & 4095;
#pragma unroll
            for (int fj = 0; fj < 4; ++fj) {
                int n = col0 + wc + fj * 16 + lane15;
                int h = n >> 6, d = n & 63;
                Qb[((size_t)(b_ * H_ + h) * T_ + t) * 64 + d] = f2bf(acc[fi][fj][j]);
            }
        }
}

// ---------------------------------------------------------------------------
// K/V GEMM swapped: C[m=(h,d)][n=token] = W @ x^T  -> KT/VT[bh][d][t].
// A'' = [whi|whi|wlo], B'' = [xhi|xlo|xhi].
// Grid (128 token-panels, 8 row-panels, 2): token-panel sharers (y=0..7, z=0/1)
// have wgid stride 128/1024 == 0 mod 8 -> SAME XCD -> x panel fetched once
// per XCD L2 instead of 8x (round-8 counter: FETCH 800MB vs 73MB ideal).
// ---------------------------------------------------------------------------
__global__ __launch_bounds__(256)
void kv_mfma(const u16* __restrict__ xhi, const u16* __restrict__ xlo,
             const u16* __restrict__ hk, const u16* __restrict__ lk,
             const u16* __restrict__ hv, const u16* __restrict__ lv,
             u16* __restrict__ KT, u16* __restrict__ VT)
{
    __shared__ u16 At[128 * 64];
    __shared__ u16 Bt[128 * 64];
    int z = blockIdx.z;
    const u16* whi = z ? hv : hk;
    const u16* wlo = z ? lv : lk;
    u16* C = z ? VT : KT;

    int tid = threadIdx.x, l = tid & 63, w = tid >> 6;
    int row0 = blockIdx.y * 128, col0 = blockIdx.x * 128;   // y=(h,d) panel, x=token panel
    int wr = (w >> 1) * 64, wc = (w & 1) * 64;
    int srow = l >> 3;
    int scol = ((l & 7) ^ srow) << 3;
    int lane15 = l & 15, lhalf = l >> 4;

    f32x4 acc[4][4];
#pragma unroll
    for (int i = 0; i < 4; ++i)
#pragma unroll
        for (int j = 0; j < 4; ++j) acc[i][j] = (f32x4){0.f, 0.f, 0.f, 0.f};

    int aoff[4][2], boff[4][2];
#pragma unroll
    for (int f = 0; f < 4; ++f)
#pragma unroll
        for (int ks = 0; ks < 2; ++ks) {
            int sw = (lane15 & 7) << 3;
            aoff[f][ks] = (wr + f * 16 + lane15) * 64 + ((lhalf * 8 + ks * 32) ^ sw);
            boff[f][ks] = (wc + f * 16 + lane15) * 64 + ((lhalf * 8 + ks * 32) ^ sw);
        }

    for (int kb = 0; kb < 3072; kb += 64) {
        int seg = kb >> 10, kc = kb & 1023;
        const u16* Asrc = (seg == 2) ? wlo : whi;
        const u16* Bsrc = (seg == 1) ? xlo : xhi;
#pragma unroll
        for (int i2 = 0; i2 < 4; ++i2) {
            int c = w * 4 + i2;
            gld16(Asrc + (size_t)(row0 + c * 8 + srow) * 1024 + kc + scol, (char*)At + c * 1024);
            gld16(Bsrc + (size_t)(col0 + c * 8 + srow) * 1024 + kc + scol, (char*)Bt + c * 1024);
        }
        __syncthreads();
#pragma unroll
        for (int ks = 0; ks < 2; ++ks) {
            bf16x8 a[4], b[4];
#pragma unroll
            for (int f = 0; f < 4; ++f) a[f] = *(const bf16x8*)&At[aoff[f][ks]];
#pragma unroll
            for (int f = 0; f < 4; ++f) b[f] = *(const bf16x8*)&Bt[boff[f][ks]];
#pragma unroll
            for (int fi = 0; fi < 4; ++fi)
#pragma unroll
                for (int fj = 0; fj < 4; ++fj)
                    acc[fi][fj] = __builtin_amdgcn_mfma_f32_16x16x32_bf16(a[fi], b[fj], acc[fi][fj], 0, 0, 0);
        }
        __syncthreads();
    }
    // C[m=(h,d)][n=token] -> [bh][d][t]
#pragma unroll
    for (int fi = 0; fi < 4; ++fi)
#pragma unroll
        for (int j = 0; j < 4; ++j) {
            int m = row0 + wr + fi * 16 + lhalf * 4 + j;     // 0..1023
            int h = m >> 6, d = m & 63;
#pragma unroll
            for (int fj = 0; fj < 4; ++fj) {
                int tt = col0 + wc + fj * 16 + lane15;       // 0..16383
                int b_ = tt >> 12, t = tt & 4095;
                C[((size_t)((b_ * H_ + h) * 64 + d)) * T_ + t] = f2bf(acc[fi][fj][j]);
            }
        }
}

// ---------------------------------------------------------------------------
// Soft-hash: reads KT[bh][d][t] (coalesced), writes PT[bh][s][t] (coalesced).
// Grid: 64 bh x 16 tgroups; thread = one token.
// ---------------------------------------------------------------------------
__global__ __launch_bounds__(256)
void hash_kernel(const u16* __restrict__ KT, const float* __restrict__ planes,
                 const float* __restrict__ protos, const float* __restrict__ ltemp,
                 u16* __restrict__ PT)
{
    __shared__ float pl[2048];
    __shared__ float pr[64];
    int tid = threadIdx.x;
    for (int i = tid; i < 2048; i += 256) pl[i] = planes[i];
    if (tid < 64) pr[tid] = protos[tid];
    __syncthreads();

    float sc = __expf(ltemp[0]);
    sc = fminf(fmaxf(sc, 0.01f), 20.0f);
    float inv = 1.0f / sc;

    int bh = blockIdx.x >> 4, tg = blockIdx.x & 15;
    int t = tg * 256 + tid;
    const u16* kbase = KT + (size_t)bh * 64 * T_ + t;

    float proj[32];
#pragma unroll
    for (int p = 0; p < 32; ++p) proj[p] = 0.f;
    for (int d = 0; d < 64; ++d) {
        float kd = bf2f(kbase[(size_t)d * T_]);
#pragma unroll
        for (int p = 0; p < 32; ++p) proj[p] += kd * pl[d * 32 + p];
    }
#pragma unroll
    for (int p = 0; p < 32; ++p) {
        float e = __expf(2.f * proj[p]);
        proj[p] = (1.f - 2.f / (e + 1.f)) * inv;
    }

    u16* obase = PT + (size_t)bh * 128 * T_ + t;
    for (int lt = 0; lt < 8; ++lt) {
        float lg[16];
        float mx = -1e30f;
#pragma unroll
        for (int r = 0; r < 16; ++r) {
            float s = 0.f;
#pragma unroll
            for (int kbit = 0; kbit < 4; ++kbit) s += proj[lt * 4 + kbit] * pr[kbit * 16 + r];
            lg[r] = s; mx = fmaxf(mx, s);
        }
        float sum = 0.f;
#pragma unroll
        for (int r = 0; r < 16; ++r) { lg[r] = __expf(lg[r] - mx); sum += lg[r]; }
        float is = 1.f / sum;
#pragma unroll
        for (int r = 0; r < 16; ++r)
            obase[(size_t)(lt * 16 + r) * T_] = f2bf(lg[r] * is);
    }
}

// ---------------------------------------------------------------------------
// Bucket MFMA: per (chunk of 512 tokens, bh):
//   BK[s][d]  += PT[s][t] * KT[d][t]   (waves 0,1: s-halves)
//   BVT[d][s] += VT[d][t] * PT[s][t]   (waves 2,3: s-col-halves)
// partial[bh][chunk][2][8192] fp32. Grid (8, 64).
// ---------------------------------------------------------------------------
__global__ __launch_bounds__(256)
void bucket_mfma(const u16* __restrict__ PT, const u16* __restrict__ KT,
                 const u16* __restrict__ VT, float* __restrict__ partial)
{
    __shared__ u16 PTs[128 * 64];
    __shared__ u16 KTs[64 * 64];
    __shared__ u16 VTs[64 * 64];
    int tid = threadIdx.x, l = tid & 63, w = tid >> 6;
    int chunk = blockIdx.x, bh = blockIdx.y;
    int srow = l >> 3;
    int scol = ((l & 7) ^ srow) << 3;
    int lane15 = l & 15, lhalf = l >> 4;

    f32x4 acc[4][4];
#pragma unroll
    for (int i = 0; i < 4; ++i)
#pragma unroll
        for (int j = 0; j < 4; ++j) acc[i][j] = (f32x4){0.f, 0.f, 0.f, 0.f};

    // LDS operand bases per wave role
    const u16* Al = (w < 2) ? PTs : VTs;
    const u16* Bl = (w < 2) ? KTs : PTs;
    int arow0 = (w < 2) ? w * 64 : 0;
    int brow0 = (w < 2) ? 0 : (w - 2) * 64;

    int aoff[4][2], boff[4][2];
#pragma unroll
    for (int f = 0; f < 4; ++f)
#pragma unroll
        for (int ks = 0; ks < 2; ++ks) {
            int sw = (lane15 & 7) << 3;
            aoff[f][ks] = (arow0 + f * 16 + lane15) * 64 + ((lhalf * 8 + ks * 32) ^ sw);
            boff[f][ks] = (brow0 + f * 16 + lane15) * 64 + ((lhalf * 8 + ks * 32) ^ sw);
        }

    const u16* PTg = PT + (size_t)bh * 128 * T_;
    const u16* KTg = KT + (size_t)bh * 64 * T_;
    const u16* VTg = VT + (size_t)bh * 64 * T_;

    for (int step = 0; step < 8; ++step) {
        int t0 = chunk * 512 + step * 64;
#pragma unroll
        for (int i2 = 0; i2 < 8; ++i2) {
            int c = w * 8 + i2;          // 0..31
            if (c < 16) {
                gld16(PTg + (size_t)(c * 8 + srow) * T_ + t0 + scol, (char*)PTs + c * 1024);
            } else if (c < 24) {
                int cc = c - 16;
                gld16(KTg + (size_t)(cc * 8 + srow) * T_ + t0 + scol, (char*)KTs + cc * 1024);
            } else {
                int cc = c - 24;
                gld16(VTg + (size_t)(cc * 8 + srow) * T_ + t0 + scol, (char*)VTs + cc * 1024);
            }
        }
        __syncthreads();
#pragma unroll
        for (int ks = 0; ks < 2; ++ks) {
            bf16x8 a[4], b[4];
#pragma unroll
            for (int f = 0; f < 4; ++f) a[f] = *(const bf16x8*)&Al[aoff[f][ks]];
#pragma unroll
            for (int f = 0; f < 4; ++f) b[f] = *(const bf16x8*)&Bl[boff[f][ks]];
#pragma unroll
            for (int fi = 0; fi < 4; ++fi)
#pragma unroll
                for (int fj = 0; fj < 4; ++fj)
                    acc[fi][fj] = __builtin_amdgcn_mfma_f32_16x16x32_bf16(a[fi], b[fj], acc[fi][fj], 0, 0, 0);
        }
        __syncthreads();
    }

    float* base = partial + (size_t)(bh * 8 + chunk) * 16384;
#pragma unroll
    for (int fi = 0; fi < 4; ++fi)
#pragma unroll
        for (int j = 0; j < 4; ++j) {
            int m = fi * 16 + lhalf * 4 + j;
#pragma unroll
            for (int fj = 0; fj < 4; ++fj) {
                int n = fj * 16 + lane15;
                if (w < 2)  base[(w * 64 + m) * 64 + n] = acc[fi][fj][j];
                else        base[8192 + m * 128 + (w - 2) * 64 + n] = acc[fi][fj][j];
            }
        }
}

// Reduce 8 chunk-partials -> hi/lo bf16: BKhi/lo[bh][128][64], BVThi/lo[bh][64][128]
__global__ __launch_bounds__(256)
void reduce_kernel(const float* __restrict__ partial,
                   u16* __restrict__ BKhi, u16* __restrict__ BKlo,
                   u16* __restrict__ BVThi, u16* __restrict__ BVTlo)
{
    int i = blockIdx.x * 256 + threadIdx.x;      // < 64*16384
    int bh = i >> 14, rem = i & 16383;
    float s = 0.f;
#pragma unroll
    for (int c = 0; c < 8; ++c) s += partial[(size_t)(bh * 8 + c) * 16384 + rem];
    u16 h = f2bf(s);
    u16 lo = f2bf(s - bf2f(h));
    if (rem < 8192) { BKhi[bh * 8192 + rem] = h;  BKlo[bh * 8192 + rem] = lo; }
    else            { BVThi[bh * 8192 + rem - 8192] = h; BVTlo[bh * 8192 + rem - 8192] = lo; }
}

// ---------------------------------------------------------------------------
// Attention scores + softmax: per (qtile 128, bh):
//   S = Q @ BK^T / 8 (hi+lo), wave-parallel softmax -> Pattn[bh][t][s] bf16.
// Grid (32, 64). Wave w owns q in [w*32, w*32+32).
// ---------------------------------------------------------------------------
__global__ __launch_bounds__(256)
void attn_scores(const u16* __restrict__ Qb, const u16* __restrict__ BKhi,
                 const u16* __restrict__ BKlo, u16* __restrict__ Pattn)
{
    __shared__ u16 Qs[128 * 64];
    __shared__ u16 Kh[128 * 64];
    __shared__ u16 Kl[128 * 64];
    int tid = threadIdx.x, l = tid & 63, w = tid >> 6;
    int qt = blockIdx.x, bh = blockIdx.y;
    int srow = l >> 3;
    int scol = ((l & 7) ^ srow) << 3;
    int lane15 = l & 15, lhalf = l >> 4;

    const u16* Qg = Qb + ((size_t)bh * T_ + qt * 128) * 64;
    const u16* Khg = BKhi + (size_t)bh * 8192;
    const u16* Klg = BKlo + (size_t)bh * 8192;

#pragma unroll
    for (int i2 = 0; i2 < 12; ++i2) {
        int c = w * 12 + i2;            // 0..47
        if (c < 16)      gld16(Qg  + (size_t)(c * 8 + srow) * 64 + scol,        (char*)Qs + c * 1024);
        else if (c < 32) gld16(Khg + (size_t)((c-16) * 8 + srow) * 64 + scol,   (char*)Kh + (c-16) * 1024);
        else             gld16(Klg + (size_t)((c-32) * 8 + srow) * 64 + scol,   (char*)Kl + (c-32) * 1024);
    }
    __syncthreads();

    f32x4 acc[2][8];
#pragma unroll
    for (int i = 0; i < 2; ++i)
#pragma unroll
        for (int j = 0; j < 8; ++j) acc[i][j] = (f32x4){0.f, 0.f, 0.f, 0.f};

    int sw = (lane15 & 7) << 3;
    bf16x8 a[2][2];
#pragma unroll
    for (int fi = 0; fi < 2; ++fi)
#pragma unroll
        for (int ks = 0; ks < 2; ++ks)
            a[fi][ks] = *(const bf16x8*)&Qs[(w * 32 + fi * 16 + lane15) * 64 + ((lhalf * 8 + ks * 32) ^ sw)];

#pragma unroll
    for (int kp = 0; kp < 2; ++kp) {
        const u16* Bl = kp ? Kl : Kh;
#pragma unroll
        for (int ks = 0; ks < 2; ++ks)
#pragma unroll
            for (int fj = 0; fj < 8; ++fj) {
                bf16x8 b = *(const bf16x8*)&Bl[(fj * 16 + lane15) * 64 + ((lhalf * 8 + ks * 32) ^ sw)];
#pragma unroll
                for (int fi = 0; fi < 2; ++fi)
                    acc[fi][fj] = __builtin_amdgcn_mfma_f32_16x16x32_bf16(a[fi][ks], b, acc[fi][fj], 0, 0, 0);
            }
    }

    // wave-parallel softmax per q-row (8 regs + shfl over lane15 bits)
    u16* Pg = Pattn + ((size_t)bh * T_ + qt * 128) * 128;
#pragma unroll
    for (int fi = 0; fi < 2; ++fi)
#pragma unroll
        for (int j = 0; j < 4; ++j) {
            float v[8];
            float mx = -1e30f;
#pragma unroll
            for (int fj = 0; fj < 8; ++fj) { v[fj] = acc[fi][fj][j] * 0.125f; mx = fmaxf(mx, v[fj]); }
            mx = fmaxf(mx, __shfl_xor(mx, 1));
            mx = fmaxf(mx, __shfl_xor(mx, 2));
            mx = fmaxf(mx, __shfl_xor(mx, 4));
            mx = fmaxf(mx, __shfl_xor(mx, 8));
            float sum = 0.f;
#pragma unroll
            for (int fj = 0; fj < 8; ++fj) { v[fj] = __expf(v[fj] - mx); sum += v[fj]; }
            sum += __shfl_xor(sum, 1);
            sum += __shfl_xor(sum, 2);
            sum += __shfl_xor(sum, 4);
            sum += __shfl_xor(sum, 8);
            float is = 1.f / sum;
            int q = w * 32 + fi * 16 + lhalf * 4 + j;
#pragma unroll
            for (int fj = 0; fj < 8; ++fj)
                Pg[(size_t)q * 128 + fj * 16 + lane15] = f2bf(v[fj] * is);
        }
}

// ---------------------------------------------------------------------------
// PV: O = P @ BVT^T (hi+lo) -> AO[(b,t)][(h,d)] bf16. Grid (32, 64).
// LDS: Ps[128][128] + BVh[64][128] + BVl[64][128] = 64 KiB.
// ---------------------------------------------------------------------------
__global__ __launch_bounds__(256)
void attn_pv(const u16* __restrict__ Pattn, const u16* __restrict__ BVThi,
             const u16* __restrict__ BVTlo, u16* __restrict__ AO)
{
    __shared__ u16 Ps[128 * 128];
    __shared__ u16 BVh[64 * 128];
    __shared__ u16 BVl[64 * 128];
    int tid = threadIdx.x, l = tid & 63, w = tid >> 6;
    int qt = blockIdx.x, bh = blockIdx.y;
    int lane15 = l & 15, lhalf = l >> 4;

    const u16* Pg = Pattn + ((size_t)bh * T_ + qt * 128) * 128;
    const u16* Vh = BVThi + (size_t)bh * 8192;
    const u16* Vl = BVTlo + (size_t)bh * 8192;

    // 128-elem rows: chunk = 4 rows; lane row = l>>4, granule = l&15.
#pragma unroll
    for (int i2 = 0; i2 < 16; ++i2) {
        int c = w * 16 + i2;            // 0..63
        int rl = l >> 4;
        if (c < 32) {
            int row = c * 4 + rl;
            int g = ((l & 15) ^ (row & 7)) << 3;
            gld16(Pg + (size_t)row * 128 + g, (char*)Ps + c * 1024);
        } else if (c < 48) {
            int cc = c - 32;
            int row = cc * 4 + rl;
            int g = ((l & 15) ^ (row & 7)) << 3;
            gld16(Vh + (size_t)row * 128 + g, (char*)BVh + cc * 1024);
        } else {
            int cc = c - 48;
            int row = cc * 4 + rl;
            int g = ((l & 15) ^ (row & 7)) << 3;
            gld16(Vl + (size_t)row * 128 + g, (char*)BVl + cc * 1024);
        }
    }
    __syncthreads();

    f32x4 acc[2][4];
#pragma unroll
    for (int i = 0; i < 2; ++i)
#pragma unroll
        for (int j = 0; j < 4; ++j) acc[i][j] = (f32x4){0.f, 0.f, 0.f, 0.f};

    int sw = (lane15 & 7) << 3;
    bf16x8 a[4][2];
#pragma unroll
    for (int ks = 0; ks < 4; ++ks)
#pragma unroll
        for (int fi = 0; fi < 2; ++fi)
            a[ks][fi] = *(const bf16x8*)&Ps[(w * 32 + fi * 16 + lane15) * 128 + ((lhalf * 8 + ks * 32) ^ sw)];

#pragma unroll
    for (int kk = 0; kk < 8; ++kk) {
        int ks = kk & 3;
        const u16* Bl = (kk < 4) ? BVh : BVl;
#pragma unroll
        for (int fj = 0; fj < 4; ++fj) {
            bf16x8 b = *(const bf16x8*)&Bl[(fj * 16 + lane15) * 128 + ((lhalf * 8 + ks * 32) ^ sw)];
#pragma unroll
            for (int fi = 0; fi < 2; ++fi)
                acc[fi][fj] = __builtin_amdgcn_mfma_f32_16x16x32_bf16(a[ks][fi], b, acc[fi][fj], 0, 0, 0);
        }
    }

    int b_ = bh >> 4, h = bh & 15;
#pragma unroll
    for (int fi = 0; fi < 2; ++fi)
#pragma unroll
        for (int j = 0; j < 4; ++j) {
            int t = qt * 128 + w * 32 + fi * 16 + lhalf * 4 + j;
#pragma unroll
            for (int fj = 0; fj < 4; ++fj) {
                int d = fj * 16 + lane15;
                AO[((size_t)(b_ * T_ + t)) * DK_ + h * 64 + d] = f2bf(acc[fi][fj][j]);
            }
        }
}

// ---------------------------------------------------------------------------
// Output GEMM: out = AO @ [Wohi|Wolo]^T + bo, fp32 out.
// ---------------------------------------------------------------------------
__global__ __launch_bounds__(256)
void out_mfma(const u16* __restrict__ AO, const u16* __restrict__ wohi,
              const u16* __restrict__ wolo, const float* __restrict__ bo,
              float* __restrict__ out)
{
    __shared__ u16 At[128 * 64];
    __shared__ u16 Bt[128 * 64];
    int tid = threadIdx.x, l = tid & 63, w = tid >> 6;
    int row0 = blockIdx.x * 128, col0 = blockIdx.y * 128;
    int wr = (w >> 1) * 64, wc = (w & 1) * 64;
    int srow = l >> 3;
    int scol = ((l & 7) ^ srow) << 3;
    int lane15 = l & 15, lhalf = l >> 4;

    f32x4 acc[4][4];
#pragma unroll
    for (int i = 0; i < 4; ++i)
#pragma unroll
        for (int j = 0; j < 4; ++j) acc[i][j] = (f32x4){0.f, 0.f, 0.f, 0.f};

    int aoff[4][2], boff[4][2];
#pragma unroll
    for (int f = 0; f < 4; ++f)
#pragma unroll
        for (int ks = 0; ks < 2; ++ks) {
            int sw = (lane15 & 7) << 3;
            aoff[f][ks] = (wr + f * 16 + lane15) * 64 + ((lhalf * 8 + ks * 32) ^ sw);
            boff[f][ks] = (wc + f * 16 + lane15) * 64 + ((lhalf * 8 + ks * 32) ^ sw);
        }

    for (int kb = 0; kb < 2048; kb += 64) {
        int seg = kb >> 10, kc = kb & 1023;
        const u16* Bsrc = seg ? wolo : wohi;
#pragma unroll
        for (int i2 = 0; i2 < 4; ++i2) {
            int c = w * 4 + i2;
            gld16(AO + (size_t)(row0 + c * 8 + srow) * 1024 + kc + scol, (char*)At + c * 1024);
            gld16(Bsrc + (size_t)(col0 + c * 8 + srow) * 1024 + kc + scol, (char*)Bt + c * 1024);
        }
        __syncthreads();
#pragma unroll
        for (int ks = 0; ks < 2; ++ks) {
            bf16x8 a[4], b[4];
#pragma unroll
            for (int f = 0; f < 4; ++f) a[f] = *(const bf16x8*)&At[aoff[f][ks]];
#pragma unroll
            for (int f = 0; f < 4; ++f) b[f] = *(const bf16x8*)&Bt[boff[f][ks]];
#pragma unroll
            for (int fi = 0; fi < 4; ++fi)
#pragma unroll
                for (int fj = 0; fj < 4; ++fj)
                    acc[fi][fj] = __builtin_amdgcn_mfma_f32_16x16x32_bf16(a[fi], b[fj], acc[fi][fj], 0, 0, 0);
        }
        __syncthreads();
    }
#pragma unroll
    for (int fi = 0; fi < 4; ++fi)
#pragma unroll
        for (int j = 0; j < 4; ++j) {
            size_t m = row0 + wr + fi * 16 + lhalf * 4 + j;
#pragma unroll
            for (int fj = 0; fj < 4; ++fj) {
                int n = col0 + wc + fj * 16 + lane15;
                out[m * DK_ + n] = acc[fi][fj][j] + bo[n];
            }
        }
}

// ---------------------------------------------------------------------------
extern "C" void kernel_launch(void* const* d_in, const int* in_sizes, int n_in,
                              void* d_out, int out_size, void* d_ws, size_t ws_size,
                              hipStream_t stream)
{
    (void)in_sizes; (void)n_in; (void)out_size; (void)ws_size;
    const float* x      = (const float*)d_in[0];
    const float* Wq     = (const float*)d_in[1];
    const float* Wk     = (const float*)d_in[2];
    const float* Wv     = (const float*)d_in[3];
    const float* Wo     = (const float*)d_in[4];
    const float* bo     = (const float*)d_in[5];
    const float* planes = (const float*)d_in[6];
    const float* protos = (const float*)d_in[7];
    const float* ltemp  = (const float*)d_in[8];
    float* out = (float*)d_out;

    char* ws = (char*)d_ws;
    u16* xhi = (u16*)(ws + 0ull);             // 33.5MB; later PT (67MB) then Pattn
    u16* xlo = (u16*)(ws + 33554432ull);
    u16* Qb  = (u16*)(ws + 67108864ull);      // 33.5MB
    u16* KT  = (u16*)(ws + 100663296ull);     // 33.5MB
    u16* VT  = (u16*)(ws + 134217728ull);     // 33.5MB
    u16* hq  = (u16*)(ws + 167772160ull);     // weight splits 12MB (dead after q/kv)
    u16* lq  = (u16*)(ws + 169869312ull);
    u16* hk  = (u16*)(ws + 171966464ull);
    u16* lk  = (u16*)(ws + 174063616ull);
    u16* hv  = (u16*)(ws + 176160768ull);
    u16* lv  = (u16*)(ws + 178257920ull);
    u16* BKhi  = (u16*)(ws + 167772160ull);   // alias w-splits (after reduce)
    u16* BKlo  = (u16*)(ws + 168820736ull);
    u16* BVThi = (u16*)(ws + 169869312ull);
    u16* BVTlo = (u16*)(ws + 170917888ull);
    u16* wohi = (u16*)(ws + 180355072ull);    // 2MB each, live till end
    u16* wolo = (u16*)(ws + 182452224ull);
    float* partial = (float*)(ws + 184549376ull);  // 33.5MB; later AO
    u16*   AO      = (u16*)(ws + 184549376ull);
    u16* PT    = (u16*)(ws + 0ull);           // 67MB, aliases xhi+xlo
    u16* Pattn = (u16*)(ws + 0ull);           // 67MB, aliases PT (after bucket)

    split_x<<<dim3(4096), 256, 0, stream>>>(x, xhi, xlo);
    split_w<<<dim3(1024, 1, 4), 256, 0, stream>>>(Wq, Wk, Wv, Wo, hq, lq, hk, lk, hv, lv, wohi, wolo);
    q_mfma<<<dim3(128, 8), 256, 0, stream>>>(xhi, xlo, hq, lq, Qb);
    kv_mfma<<<dim3(128, 8, 2), 256, 0, stream>>>(xhi, xlo, hk, lk, hv, lv, KT, VT);
    hash_kernel<<<dim3(1024), 256, 0, stream>>>(KT, planes, protos, ltemp, PT);
    bucket_mfma<<<dim3(8, 64), 256, 0, stream>>>(PT, KT, VT, partial);
    reduce_kernel<<<dim3(4096), 256, 0, stream>>>(partial, BKhi, BKlo, BVThi, BVTlo);
    attn_scores<<<dim3(32, 64), 256, 0, stream>>>(Qb, BKhi, BKlo, Pattn);
    attn_pv<<<dim3(32, 64), 256, 0, stream>>>(Pattn, BVThi, BVTlo, AO);
    out_mfma<<<dim3(128, 8), 256, 0, stream>>>(AO, wohi, wolo, bo, out);
}